// Round 6
// baseline (1119.546 us; speedup 1.0000x reference)
//
#include <hip/hip_runtime.h>
#include <hip/hip_bf16.h>

#define W_BIT 4
#define OUT_F 11008
#define IN_F 4096
#define KRANK 16
#define M_DIM 8192
#define QW_PLANE (OUT_F * IN_F / 8)

#define N_DIM OUT_F
#define K_DIM 4096
#define NKT 128            // K tiles of 32
#define NBN 43             // N_DIM / 256

typedef __attribute__((ext_vector_type(8))) short short8;
typedef __attribute__((ext_vector_type(4))) float f32x4;

__device__ __forceinline__ short f2bf(float f) {
    union { float f; unsigned u; } v;
    v.f = f;
    unsigned r = v.u + 0x7fffu + ((v.u >> 16) & 1u);
    return (short)(r >> 16);
}

__device__ __forceinline__ void async16(void* lds_p, const void* g) {
    __builtin_amdgcn_global_load_lds(
        (const __attribute__((address_space(1))) unsigned int*)g,
        (__attribute__((address_space(3))) unsigned int*)lds_p,
        16, 0, 0);
}

#define BAR() __builtin_amdgcn_s_barrier()
#define VMC(n) do { asm volatile("s_waitcnt vmcnt(" #n ")" ::: "memory"); \
                    __builtin_amdgcn_sched_barrier(0); } while (0)
#define PRIO1() __builtin_amdgcn_s_setprio(1)
#define PRIO0() __builtin_amdgcn_s_setprio(0)

// ---------------------------------------------------------------------------
// Kernel 1: x fp32 -> bf16
// ---------------------------------------------------------------------------
__global__ __launch_bounds__(256) void convert_x_kernel(
    const float* __restrict__ x, short* __restrict__ xb) {
    int tid = blockIdx.x * blockDim.x + threadIdx.x;
    int stride = gridDim.x * blockDim.x;
    const int n8 = (M_DIM * IN_F) / 8;
    for (int i = tid; i < n8; i += stride) {
        f32x4 a = ((const f32x4*)x)[2 * i];
        f32x4 b = ((const f32x4*)x)[2 * i + 1];
        short8 o;
        o[0] = f2bf(a[0]); o[1] = f2bf(a[1]); o[2] = f2bf(a[2]); o[3] = f2bf(a[3]);
        o[4] = f2bf(b[0]); o[5] = f2bf(b[1]); o[6] = f2bf(b[2]); o[7] = f2bf(b[3]);
        ((short8*)xb)[i] = o;
    }
}

// ---------------------------------------------------------------------------
// Kernel 2: reconstruct w (unchanged from passing round)
// ---------------------------------------------------------------------------
__global__ __launch_bounds__(256) void reconstruct_w_kernel(
    const int* __restrict__ qw, const float* __restrict__ u,
    const float* __restrict__ vt, short* __restrict__ wb) {
    __shared__ float vts[W_BIT][KRANK][128];
    __shared__ float us[W_BIT][KRANK][64];

    const int t = threadIdx.x;
    const int o0 = blockIdx.y * 64;
    const int c0 = blockIdx.x * 128;

    for (int idx = t; idx < W_BIT * KRANK * 128; idx += 256) {
        int i = idx >> 11;
        int rem = idx & 2047;
        int k = rem >> 7;
        int c = rem & 127;
        vts[i][k][c] = vt[(i * KRANK + k) * IN_F + c0 + c];
    }
    for (int idx = t; idx < W_BIT * KRANK * 64; idx += 256) {
        int i = idx >> 10;
        int rem = idx & 1023;
        int o = rem >> 4;
        int k = rem & 15;
        us[i][k][o] = u[((size_t)i * OUT_F + o0 + o) * KRANK + k];
    }
    __syncthreads();

    const int to = (t >> 4) * 4;
    const int tc = (t & 15) * 8;

    float wacc[4][8];
#pragma unroll
    for (int r = 0; r < 4; ++r)
#pragma unroll
        for (int c = 0; c < 8; ++c) wacc[r][c] = 0.f;

#pragma unroll
    for (int i = 0; i < W_BIT; ++i) {
        float dot[4][8];
#pragma unroll
        for (int r = 0; r < 4; ++r)
#pragma unroll
            for (int c = 0; c < 8; ++c) dot[r][c] = 0.f;

#pragma unroll
        for (int k = 0; k < KRANK; ++k) {
            f32x4 uv = *(const f32x4*)&us[i][k][to];
            f32x4 v0 = *(const f32x4*)&vts[i][k][tc];
            f32x4 v1 = *(const f32x4*)&vts[i][k][tc + 4];
#pragma unroll
            for (int r = 0; r < 4; ++r) {
#pragma unroll
                for (int c = 0; c < 4; ++c) {
                    dot[r][c]     += uv[r] * v0[c];
                    dot[r][c + 4] += uv[r] * v1[c];
                }
            }
        }
#pragma unroll
        for (int r = 0; r < 4; ++r) {
            unsigned byte = (unsigned)qw[i * QW_PLANE + (((o0 + to + r) * IN_F + c0 + tc) >> 3)];
#pragma unroll
            for (int c = 0; c < 8; ++c) {
                wacc[r][c] += ((byte >> c) & 1u) ? dot[r][c] : -dot[r][c];
            }
        }
    }

#pragma unroll
    for (int r = 0; r < 4; ++r) {
        short8 o8;
#pragma unroll
        for (int c = 0; c < 8; ++c) o8[c] = f2bf(wacc[r][c]);
        *(short8*)&wb[(size_t)(o0 + to + r) * IN_F + c0 + tc] = o8;
    }
}

// ---------------------------------------------------------------------------
// Kernel 3: C[M,N] = A @ B^T, 128x256 tile, BK=32, 8 waves (2m x 4n of 64x64),
// TRIPLE-buffered 72 KiB LDS -> 2 blocks/CU (cross-block overlap covers the
// barrier/gate stalls, m97/m114 mechanism). One phase per K-tile:
// {8 ds_read, 3 global_load_lds (stage tile g+2), 16 MFMA (16x16x32),
//  counted vmcnt(3), barrier}. 2-iteration staging lead; never vmcnt(0) in
// steady state. Granule-XOR swizzle (verified 0-conflict in R4) both-sides.
// LDS (shorts): A slot j @ j*4096 (128r x 32k); B slot j @ 12288 + j*8192
// (256r x 32k). Total 36864 shorts = 72 KiB.
// ---------------------------------------------------------------------------
__global__ __launch_bounds__(512, 4) void gemm128x256_kernel(
    const short* __restrict__ A, const short* __restrict__ B, float* __restrict__ C) {
    extern __shared__ short lds[];

    const int t = threadIdx.x;
    const int lane = t & 63, wid = t >> 6;
    const int wr = wid >> 2, wc = wid & 3;       // 2m x 4n waves, each 64x64
    const int fr = lane & 15, fq = lane >> 4;

    const int bid = blockIdx.x;
    const int cpx = gridDim.x >> 3;              // grid 2752 % 8 == 0 -> 344
    const int swz = (bid & 7) * cpx + (bid >> 3);
    const int bm = swz / NBN, bn = swz % NBN;
    const long row0 = (long)bm * 128, col0 = (long)bn * 256;

    // fragment read offsets (granule-XOR swizzle, rows are 32 shorts = 64 B)
    const int colswz = (fq ^ ((fr >> 1) & 3)) * 8;
    const int aoff = (wr * 64 + fr) * 32 + colswz;
    const int boff = (wc * 64 + fr) * 32 + colswz;

    // staging: linear LDS dest, inverse-swizzled global source
    const int srow = t >> 2;                                 // 0..127
    const int sswz = (((t & 3) ^ ((srow >> 1) & 3)) << 3);   // shorts
    const short* pA  = A + (row0 + srow) * (size_t)K_DIM + sswz;
    const short* pB0 = B + (col0 + srow) * (size_t)K_DIM + sswz;
    const short* pB1 = pB0 + (size_t)128 * K_DIM;
    const int ldst = t * 8;                                  // shorts

    f32x4 acc[4][4];
#pragma unroll
    for (int m = 0; m < 4; ++m)
#pragma unroll
        for (int n = 0; n < 4; ++n) acc[m][n] = (f32x4)0.f;

    short8 af[4], bf[4];

// stage one K-tile into slot S: A 1 gll + B 2 gll; COLB = byte column offset
#define STG3(S, COLB) do {                                                  \
    async16(&lds[(S) * 4096 + ldst], (const char*)pA + (COLB));             \
    async16(&lds[12288 + (S) * 8192 + ldst], (const char*)pB0 + (COLB));    \
    async16(&lds[12288 + (S) * 8192 + 4096 + ldst], (const char*)pB1 + (COLB)); \
} while (0)

#define RDF(RS) do {                                                        \
    _Pragma("unroll") for (int n = 0; n < 4; ++n)                           \
        bf[n] = *(const short8*)&lds[12288 + (RS) * 8192 + boff + n * 512]; \
    _Pragma("unroll") for (int m = 0; m < 4; ++m)                           \
        af[m] = *(const short8*)&lds[(RS) * 4096 + aoff + m * 512];         \
} while (0)

#define MMA16() do { PRIO1();                                               \
    _Pragma("unroll") for (int m = 0; m < 4; ++m)                           \
        _Pragma("unroll") for (int n = 0; n < 4; ++n)                       \
            acc[m][n] = __builtin_amdgcn_mfma_f32_16x16x32_bf16(            \
                af[m], bf[n], acc[m][n], 0, 0, 0);                          \
    PRIO0(); } while (0)

// one K-tile: read slot RS, stage tile (base+O+2) into slot SS, compute, gate
#define BODY(RS, SS, O) do {                                                \
    RDF(RS);                                                                \
    STG3(SS, ((O) + 2) * 64);                                               \
    MMA16();                                                                \
    VMC(3);                                                                 \
    BAR();                                                                  \
} while (0)

    // ---- prologue: stage tiles 0 -> slot 0, 1 -> slot 1
    STG3(0, 0);
    STG3(1, 64);
    VMC(3);          // tile 0 landed (tile 1's 3 still in flight)
    BAR();

    // ---- main loop: 42 triples = tiles 0..125 (slots rotate 0,1,2)
    for (int it = 0; it < 42; ++it) {
        BODY(0, 2, 0);   // tile base+0, stage base+2 -> slot 2
        BODY(1, 0, 1);   // tile base+1, stage base+3 -> slot 0
        BODY(2, 1, 2);   // tile base+2, stage base+4 -> slot 1
        pA += 96; pB0 += 96; pB1 += 96;   // advance 3 K-tiles (192 B)
    }

    // ---- tail: tiles 126 (slot 0), 127 (slot 1); no staging
    RDF(0); MMA16();
    VMC(0);          // tile 127's loads landed
    BAR();
    RDF(1); MMA16();

    // ---- epilogue: C/D layout col = lane&15, row = (lane>>4)*4 + j
#pragma unroll
    for (int m = 0; m < 4; ++m) {
#pragma unroll
        for (int n = 0; n < 4; ++n) {
            f32x4 v = acc[m][n];
            long r0 = row0 + wr * 64 + m * 16 + fq * 4;
            long cc = col0 + wc * 64 + n * 16 + fr;
#pragma unroll
            for (int jj = 0; jj < 4; ++jj)
                C[(size_t)(r0 + jj) * N_DIM + cc] = v[jj];
        }
    }
#undef STG3
#undef RDF
#undef MMA16
#undef BODY
}

// ---------------------------------------------------------------------------
extern "C" void kernel_launch(void* const* d_in, const int* in_sizes, int n_in,
                              void* d_out, int out_size, void* d_ws, size_t ws_size,
                              hipStream_t stream) {
    const float* x  = (const float*)d_in[0];
    const int*   qw = (const int*)d_in[1];
    const float* u  = (const float*)d_in[2];
    const float* vt = (const float*)d_in[3];
    float* out = (float*)d_out;

    const size_t wb_bytes = (size_t)OUT_F * IN_F * 2;
    short* wb = (short*)d_ws;
    short* xb = (short*)((char*)d_ws + wb_bytes);

    // 72 KiB dynamic LDS -> 2 blocks/CU (host-side attribute, capture-safe)
    (void)hipFuncSetAttribute((const void*)gemm128x256_kernel,
                              hipFuncAttributeMaxDynamicSharedMemorySize, 73728);

    hipLaunchKernelGGL(convert_x_kernel, dim3(2048), dim3(256), 0, stream, x, xb);
    hipLaunchKernelGGL(reconstruct_w_kernel, dim3(IN_F / 128, OUT_F / 64), dim3(256), 0, stream,
                       qw, u, vt, wb);
    hipLaunchKernelGGL(gemm128x256_kernel, dim3((M_DIM / 128) * (N_DIM / 256)), dim3(512), 73728,
                       stream, xb, wb, out);
}

// Round 7
// 1028.088 us; speedup vs baseline: 1.0890x; 1.0890x over previous
//
#include <hip/hip_runtime.h>
#include <hip/hip_bf16.h>

#define W_BIT 4
#define OUT_F 11008
#define IN_F 4096
#define KRANK 16
#define M_DIM 8192
#define QW_PLANE (OUT_F * IN_F / 8)

#define N_DIM OUT_F
#define K_DIM 4096
#define NBN 43             // N_DIM / 256
#define RW_BLOCKS 5504     // (IN_F/128) * (OUT_F/64)

typedef __attribute__((ext_vector_type(8))) short short8;
typedef __attribute__((ext_vector_type(4))) float f32x4;

__device__ __forceinline__ short f2bf(float f) {
    union { float f; unsigned u; } v;
    v.f = f;
    unsigned r = v.u + 0x7fffu + ((v.u >> 16) & 1u);
    return (short)(r >> 16);
}

__device__ __forceinline__ void async16(void* lds_p, const void* g) {
    __builtin_amdgcn_global_load_lds(
        (const __attribute__((address_space(1))) unsigned int*)g,
        (__attribute__((address_space(3))) unsigned int*)lds_p,
        16, 0, 0);
}

#define BAR() __builtin_amdgcn_s_barrier()
#define SBAR0() __builtin_amdgcn_sched_barrier(0)
#define LGKM(n) do { asm volatile("s_waitcnt lgkmcnt(" #n ")" ::: "memory"); \
                     __builtin_amdgcn_sched_barrier(0); } while (0)
#define VMC(n) do { asm volatile("s_waitcnt vmcnt(" #n ")" ::: "memory"); \
                    __builtin_amdgcn_sched_barrier(0); } while (0)
#define PRIO1() __builtin_amdgcn_s_setprio(1)
#define PRIO0() __builtin_amdgcn_s_setprio(0)

// ---------------------------------------------------------------------------
// Fused prep: blocks [0, RW_BLOCKS) reconstruct w; rest convert x -> bf16.
// ---------------------------------------------------------------------------
__global__ __launch_bounds__(256) void prep_kernel(
    const float* __restrict__ x, const int* __restrict__ qw,
    const float* __restrict__ u, const float* __restrict__ vt,
    short* __restrict__ xb, short* __restrict__ wb) {
    const int b = blockIdx.x;
    const int t = threadIdx.x;

    if (b >= RW_BLOCKS) {
        // ---- convert x (1024 blocks, grid-stride)
        const int n8 = (M_DIM * IN_F) / 8;
        int tid = (b - RW_BLOCKS) * 256 + t;
        for (int i = tid; i < n8; i += 1024 * 256) {
            f32x4 a = ((const f32x4*)x)[2 * i];
            f32x4 c = ((const f32x4*)x)[2 * i + 1];
            short8 o;
            o[0] = f2bf(a[0]); o[1] = f2bf(a[1]); o[2] = f2bf(a[2]); o[3] = f2bf(a[3]);
            o[4] = f2bf(c[0]); o[5] = f2bf(c[1]); o[6] = f2bf(c[2]); o[7] = f2bf(c[3]);
            ((short8*)xb)[i] = o;
        }
        return;
    }

    // ---- reconstruct w: tile 64 o-rows x 128 in-cols
    __shared__ float vts[W_BIT][KRANK][128];
    __shared__ float us[W_BIT][KRANK][64];

    const int c0 = (b & 31) * 128;
    const int o0 = (b >> 5) * 64;

    for (int idx = t; idx < W_BIT * KRANK * 128; idx += 256) {
        int i = idx >> 11, rem = idx & 2047, k = rem >> 7, c = rem & 127;
        vts[i][k][c] = vt[(i * KRANK + k) * IN_F + c0 + c];
    }
    for (int idx = t; idx < W_BIT * KRANK * 64; idx += 256) {
        int i = idx >> 10, rem = idx & 1023, o = rem >> 4, k = rem & 15;
        us[i][k][o] = u[((size_t)i * OUT_F + o0 + o) * KRANK + k];
    }
    __syncthreads();

    const int to = (t >> 4) * 4;
    const int tc = (t & 15) * 8;

    float wacc[4][8];
#pragma unroll
    for (int r = 0; r < 4; ++r)
#pragma unroll
        for (int c = 0; c < 8; ++c) wacc[r][c] = 0.f;

#pragma unroll
    for (int i = 0; i < W_BIT; ++i) {
        float dot[4][8];
#pragma unroll
        for (int r = 0; r < 4; ++r)
#pragma unroll
            for (int c = 0; c < 8; ++c) dot[r][c] = 0.f;
#pragma unroll
        for (int k = 0; k < KRANK; ++k) {
            f32x4 uv = *(const f32x4*)&us[i][k][to];
            f32x4 v0 = *(const f32x4*)&vts[i][k][tc];
            f32x4 v1 = *(const f32x4*)&vts[i][k][tc + 4];
#pragma unroll
            for (int r = 0; r < 4; ++r) {
#pragma unroll
                for (int c = 0; c < 4; ++c) {
                    dot[r][c]     += uv[r] * v0[c];
                    dot[r][c + 4] += uv[r] * v1[c];
                }
            }
        }
#pragma unroll
        for (int r = 0; r < 4; ++r) {
            unsigned byte = (unsigned)qw[i * QW_PLANE + (((o0 + to + r) * IN_F + c0 + tc) >> 3)];
#pragma unroll
            for (int c = 0; c < 8; ++c)
                wacc[r][c] += ((byte >> c) & 1u) ? dot[r][c] : -dot[r][c];
        }
    }
#pragma unroll
    for (int r = 0; r < 4; ++r) {
        short8 o8;
#pragma unroll
        for (int c = 0; c < 8; ++c) o8[c] = f2bf(wacc[r][c]);
        *(short8*)&wb[(size_t)(o0 + to + r) * IN_F + c0 + tc] = o8;
    }
}

// ---------------------------------------------------------------------------
// GEMM: C[M,N] = A @ B^T, 256x256 tile, BK=64, 4 waves (2x2) of 128x128.
// Full-phase read-ahead: every phase issues NEXT phase's fragment reads into
// ping-pong reg sets, waits LGKM(#just-issued) -> consumed reads were issued
// a full phase earlier (~0 drain). 4 gll/phase (one 16 KB slot), vmcnt gates
// VMC(12)@phB / VMC(16)@phD give >=5-phase staging lead. Granule-XOR swizzle
// (R4-verified 0-conflict). LDS 128 KiB = 8 slots x 8192 shorts:
// A[buf][kh] @ (buf*2+kh)*8192, B[buf][kh] @ 32768 + (buf*2+kh)*8192.
// ---------------------------------------------------------------------------
__global__ __launch_bounds__(256, 1) void gemm256_kernel(
    const short* __restrict__ A, const short* __restrict__ B, float* __restrict__ C) {
    extern __shared__ short lds[];

    const int t = threadIdx.x;
    const int lane = t & 63, wid = t >> 6;
    const int wr = wid >> 1, wc = wid & 1;       // 2 x 2 waves, each 128x128
    const int fr = lane & 15, fq = lane >> 4;

    const int bid = blockIdx.x;
    const int cpx = gridDim.x >> 3;              // grid 1376 % 8 == 0
    const int swzb = (bid & 7) * cpx + (bid >> 3);
    const int bm = swzb / NBN, bn = swzb % NBN;
    const long row0 = (long)bm * 256, col0 = (long)bn * 256;

    // fragment read bases (granule-XOR swizzle; rows = 32 shorts = 64 B)
    const int colswz = (fq ^ ((fr >> 1) & 3)) * 8;
    const int aoff = (wr * 128 + fr) * 32 + colswz;
    const int boff = (wc * 128 + fr) * 32 + colswz;

    // staging: linear LDS dest, inverse-swizzled global source (256 threads)
    const int srow = t >> 2;                                 // 0..63 (+64j)
    const int gswz = ((t & 3) ^ ((t >> 3) & 3)) << 3;        // shorts
    const short* pA = A + (row0 + srow) * (size_t)K_DIM + gswz;
    const short* pB = B + (col0 + srow) * (size_t)K_DIM + gswz;

    f32x4 acc[8][8];
#pragma unroll
    for (int m = 0; m < 8; ++m)
#pragma unroll
        for (int n = 0; n < 8; ++n) acc[m][n] = (f32x4)0.f;

    short8 afA[8], afB[8], bfA[4], bfB[4];

// stage one 16 KB slot: 4 gll, rows srow + 64j
#define STGA(SLOT, OFFB) do {                                               \
    _Pragma("unroll") for (int j_ = 0; j_ < 4; ++j_)                        \
        async16(&lds[(SLOT) + (j_ * 256 + t) * 8],                          \
                (const char*)pA + (size_t)j_ * 64 * K_DIM * 2 + (OFFB));    \
} while (0)
#define STGB(SLOT, OFFB) do {                                               \
    _Pragma("unroll") for (int j_ = 0; j_ < 4; ++j_)                        \
        async16(&lds[(SLOT) + (j_ * 256 + t) * 8],                          \
                (const char*)pB + (size_t)j_ * 64 * K_DIM * 2 + (OFFB));    \
} while (0)

#define RDA(SET, SLOT) do {                                                 \
    _Pragma("unroll") for (int m_ = 0; m_ < 8; ++m_)                        \
        SET[m_] = *(const short8*)&lds[(SLOT) + aoff + m_ * 512];           \
} while (0)
#define RDB(SET, SLOT, NH) do {                                             \
    _Pragma("unroll") for (int n_ = 0; n_ < 4; ++n_)                        \
        SET[n_] = *(const short8*)&lds[(SLOT) + boff + (NH) * 2048 + n_ * 512]; \
} while (0)

#define MMA(AF, BF, NH) do { PRIO1();                                       \
    _Pragma("unroll") for (int m_ = 0; m_ < 8; ++m_)                        \
        _Pragma("unroll") for (int n_ = 0; n_ < 4; ++n_)                    \
            acc[m_][(NH) * 4 + n_] = __builtin_amdgcn_mfma_f32_16x16x32_bf16( \
                AF[m_], BF[n_], acc[m_][(NH) * 4 + n_], 0, 0, 0);           \
    PRIO0(); SBAR0(); } while (0)

// steady-state tile: CA0/CA1/CB0/CB1 = this tile's slots; NA0/NB0 = next
// tile's kk0 slots (phD read-ahead); SBX = other-buf B kk1 slot (phA stage);
// P = byte offset parity (0 even tile, 128 odd).
#define TILE(CA0, CA1, CB0, CB1, NA0, NB0, SBX, P) do {                     \
    /* phA */                                                               \
    RDB(bfB, CB0, 1); STGB(SBX, 192 + (P));                                 \
    BAR(); LGKM(4);  MMA(afA, bfA, 0); BAR();                               \
    /* phB */                                                               \
    VMC(12); RDA(afB, CA1); RDB(bfA, CB1, 0); STGA(CA0, 256 + (P));         \
    BAR(); LGKM(12); MMA(afA, bfB, 1); BAR();                               \
    /* phC */                                                               \
    RDB(bfB, CB1, 1); STGB(CB0, 256 + (P));                                 \
    BAR(); LGKM(4);  MMA(afB, bfA, 0); BAR();                               \
    /* phD */                                                               \
    VMC(16); RDA(afA, NA0); RDB(bfA, NB0, 0); STGA(CA1, 320 + (P));         \
    BAR(); LGKM(12); MMA(afB, bfB, 1); BAR();                               \
} while (0)

    // ---- prologue: 7 slot batches (28 gll), then first read-ahead
    STGA(0,     0);    // A(0,kk0)
    STGA(8192,  64);   // A(0,kk32)
    STGB(32768, 0);    // B(0,kk0)
    STGB(40960, 64);   // B(0,kk32)
    STGA(16384, 128);  // A(1,kk0)
    STGB(49152, 128);  // B(1,kk0)
    STGA(24576, 192);  // A(1,kk32)
    VMC(12);           // tile0's 4 batches landed
    BAR();
    RDA(afA, 0);       // R(phA tile0)
    RDB(bfA, 32768, 0);

    // ---- main loop: 31 iterations x 2 tiles (tiles 0..61)
    for (int it = 0; it < 31; ++it) {
        TILE(0,     8192,  32768, 40960, 16384, 49152, 57344, 0);    // even
        TILE(16384, 24576, 49152, 57344, 0,     32768, 40960, 128);  // odd
        pA += 128; pB += 128;   // advance 2 K-tiles (256 B)
    }

    // ---- tail: tile 62 (buf0)
    RDB(bfB, 32768, 1); STGB(57344, 192);                 // stage B(63,kk32)
    BAR(); LGKM(4);  MMA(afA, bfA, 0); BAR();
    VMC(12); RDA(afB, 8192); RDB(bfA, 40960, 0);
    BAR(); LGKM(12); MMA(afA, bfB, 1); BAR();
    RDB(bfB, 40960, 1);
    BAR(); LGKM(4);  MMA(afB, bfA, 0); BAR();
    VMC(8);  RDA(afA, 16384); RDB(bfA, 49152, 0);         // A(63,0),B(63,0) landed
    BAR(); LGKM(12); MMA(afB, bfB, 1); BAR();
    // ---- tile 63 (buf1)
    RDB(bfB, 49152, 1);
    BAR(); LGKM(4);  MMA(afA, bfA, 0); BAR();
    VMC(0);  RDA(afB, 24576); RDB(bfA, 57344, 0);         // B(63,kk32) landed
    BAR(); LGKM(12); MMA(afA, bfB, 1); BAR();
    RDB(bfB, 57344, 1);
    BAR(); LGKM(4);  MMA(afB, bfA, 0); BAR();
    BAR(); LGKM(0);  MMA(afB, bfB, 1);

    // ---- epilogue: C/D layout col = lane&15, row = (lane>>4)*4 + j
#pragma unroll
    for (int m = 0; m < 8; ++m) {
#pragma unroll
        for (int n = 0; n < 8; ++n) {
            f32x4 v = acc[m][n];
            long r0 = row0 + wr * 128 + m * 16 + fq * 4;
            long cc = col0 + wc * 128 + n * 16 + fr;
#pragma unroll
            for (int jj = 0; jj < 4; ++jj)
                C[(size_t)(r0 + jj) * N_DIM + cc] = v[jj];
        }
    }
#undef STGA
#undef STGB
#undef RDA
#undef RDB
#undef MMA
#undef TILE
}

// ---------------------------------------------------------------------------
extern "C" void kernel_launch(void* const* d_in, const int* in_sizes, int n_in,
                              void* d_out, int out_size, void* d_ws, size_t ws_size,
                              hipStream_t stream) {
    const float* x  = (const float*)d_in[0];
    const int*   qw = (const int*)d_in[1];
    const float* u  = (const float*)d_in[2];
    const float* vt = (const float*)d_in[3];
    float* out = (float*)d_out;

    const size_t wb_bytes = (size_t)OUT_F * IN_F * 2;
    short* wb = (short*)d_ws;
    short* xb = (short*)((char*)d_ws + wb_bytes);

    (void)hipFuncSetAttribute((const void*)gemm256_kernel,
                              hipFuncAttributeMaxDynamicSharedMemorySize, 131072);

    hipLaunchKernelGGL(prep_kernel, dim3(RW_BLOCKS + 1024), dim3(256), 0, stream,
                       x, qw, u, vt, xb, wb);
    hipLaunchKernelGGL(gemm256_kernel, dim3((M_DIM / 256) * (N_DIM / 256)), dim3(256), 131072,
                       stream, xb, wb, out);
}

// Round 8
// 881.738 us; speedup vs baseline: 1.2697x; 1.1660x over previous
//
#include <hip/hip_runtime.h>
#include <hip/hip_bf16.h>

#define W_BIT 4
#define OUT_F 11008
#define IN_F 4096
#define KRANK 16
#define M_DIM 8192
#define QW_PLANE (OUT_F * IN_F / 8)

#define N_DIM OUT_F
#define K_DIM 4096
#define NT 64              // K tiles of 64
#define NBN 43             // N_DIM / 256

typedef __attribute__((ext_vector_type(8))) short short8;
typedef __attribute__((ext_vector_type(4))) float f32x4;

__device__ __forceinline__ short f2bf(float f) {
    union { float f; unsigned u; } v;
    v.f = f;
    unsigned r = v.u + 0x7fffu + ((v.u >> 16) & 1u);
    return (short)(r >> 16);
}

__device__ __forceinline__ void async16(void* lds_p, const void* g) {
    __builtin_amdgcn_global_load_lds(
        (const __attribute__((address_space(1))) unsigned int*)g,
        (__attribute__((address_space(3))) unsigned int*)lds_p,
        16, 0, 0);
}

#define BAR() __builtin_amdgcn_s_barrier()
#define LGKM0() do { asm volatile("s_waitcnt lgkmcnt(0)" ::: "memory"); \
                     __builtin_amdgcn_sched_barrier(0); } while (0)
#define VMC(n) do { asm volatile("s_waitcnt vmcnt(" #n ")" ::: "memory"); \
                    __builtin_amdgcn_sched_barrier(0); } while (0)
#define PRIO1() __builtin_amdgcn_s_setprio(1)
#define PRIO0() __builtin_amdgcn_s_setprio(0)

// ---------------------------------------------------------------------------
// Kernel 1: x fp32 -> bf16
// ---------------------------------------------------------------------------
__global__ __launch_bounds__(256) void convert_x_kernel(
    const float* __restrict__ x, short* __restrict__ xb) {
    int tid = blockIdx.x * blockDim.x + threadIdx.x;
    int stride = gridDim.x * blockDim.x;
    const int n8 = (M_DIM * IN_F) / 8;
    for (int i = tid; i < n8; i += stride) {
        f32x4 a = ((const f32x4*)x)[2 * i];
        f32x4 b = ((const f32x4*)x)[2 * i + 1];
        short8 o;
        o[0] = f2bf(a[0]); o[1] = f2bf(a[1]); o[2] = f2bf(a[2]); o[3] = f2bf(a[3]);
        o[4] = f2bf(b[0]); o[5] = f2bf(b[1]); o[6] = f2bf(b[2]); o[7] = f2bf(b[3]);
        ((short8*)xb)[i] = o;
    }
}

// ---------------------------------------------------------------------------
// Kernel 2: reconstruct w (unchanged from passing rounds)
// ---------------------------------------------------------------------------
__global__ __launch_bounds__(256) void reconstruct_w_kernel(
    const int* __restrict__ qw, const float* __restrict__ u,
    const float* __restrict__ vt, short* __restrict__ wb) {
    __shared__ float vts[W_BIT][KRANK][128];
    __shared__ float us[W_BIT][KRANK][64];

    const int t = threadIdx.x;
    const int o0 = blockIdx.y * 64;
    const int c0 = blockIdx.x * 128;

    for (int idx = t; idx < W_BIT * KRANK * 128; idx += 256) {
        int i = idx >> 11, rem = idx & 2047, k = rem >> 7, c = rem & 127;
        vts[i][k][c] = vt[(i * KRANK + k) * IN_F + c0 + c];
    }
    for (int idx = t; idx < W_BIT * KRANK * 64; idx += 256) {
        int i = idx >> 10, rem = idx & 1023, o = rem >> 4, k = rem & 15;
        us[i][k][o] = u[((size_t)i * OUT_F + o0 + o) * KRANK + k];
    }
    __syncthreads();

    const int to = (t >> 4) * 4;
    const int tc = (t & 15) * 8;

    float wacc[4][8];
#pragma unroll
    for (int r = 0; r < 4; ++r)
#pragma unroll
        for (int c = 0; c < 8; ++c) wacc[r][c] = 0.f;

#pragma unroll
    for (int i = 0; i < W_BIT; ++i) {
        float dot[4][8];
#pragma unroll
        for (int r = 0; r < 4; ++r)
#pragma unroll
            for (int c = 0; c < 8; ++c) dot[r][c] = 0.f;
#pragma unroll
        for (int k = 0; k < KRANK; ++k) {
            f32x4 uv = *(const f32x4*)&us[i][k][to];
            f32x4 v0 = *(const f32x4*)&vts[i][k][tc];
            f32x4 v1 = *(const f32x4*)&vts[i][k][tc + 4];
#pragma unroll
            for (int r = 0; r < 4; ++r) {
#pragma unroll
                for (int c = 0; c < 4; ++c) {
                    dot[r][c]     += uv[r] * v0[c];
                    dot[r][c + 4] += uv[r] * v1[c];
                }
            }
        }
#pragma unroll
        for (int r = 0; r < 4; ++r) {
            unsigned byte = (unsigned)qw[i * QW_PLANE + (((o0 + to + r) * IN_F + c0 + tc) >> 3)];
#pragma unroll
            for (int c = 0; c < 8; ++c)
                wacc[r][c] += ((byte >> c) & 1u) ? dot[r][c] : -dot[r][c];
        }
    }
#pragma unroll
    for (int r = 0; r < 4; ++r) {
        short8 o8;
#pragma unroll
        for (int c = 0; c < 8; ++c) o8[c] = f2bf(wacc[r][c]);
        *(short8*)&wb[(size_t)(o0 + to + r) * IN_F + c0 + tc] = o8;
    }
}

// ---------------------------------------------------------------------------
// Kernel 3: R4 schedule (best measured) with two edits:
//  (1) ONE barrier per phase (post-MFMA barrier removed) -> waves skew within
//      a phase, so a wave's next-phase ds_reads are served under the other
//      wave's MFMA window (per-SIMD pipe sharing).
//  (2) vmcnt gates only at ph4/ph8, vmcnt(4): at each gate exactly the next
//      tile's 4 halves are guaranteed landed, 2 halves (4 gll) in flight.
// Geometry: 256x256 tile, BK=64, 8 waves (2x4), K-half slots [256r][32k],
// granule-XOR swizzle (HW-verified 0 bank conflicts), 2 gll staged per phase.
// ---------------------------------------------------------------------------
__global__ __launch_bounds__(512, 2) void gemm256_kernel(
    const short* __restrict__ A, const short* __restrict__ B, float* __restrict__ C) {
    extern __shared__ short lds[];

    const int t = threadIdx.x;
    const int lane = t & 63, wid = t >> 6;
    const int wr = wid >> 2, wc = wid & 3;       // 2 x 4 wave grid
    const int fr = lane & 15, fq = lane >> 4;

    const int bid = blockIdx.x;
    const int cpx = gridDim.x >> 3;              // grid 1376 % 8 == 0
    const int swzb = (bid & 7) * cpx + (bid >> 3);
    const int bm = swzb / NBN, bn = swzb % NBN;
    const long row0 = (long)bm * 256, col0 = (long)bn * 256;

    // ---- fragment read bases (granule-XOR swizzle, lane-constant)
    const int colswz = (fq ^ ((fr >> 1) & 3)) * 8;          // shorts in 32-col row
    const int aoff = (wr * 128 + fr) * 32 + colswz;         // A region at 0
    const int boff = 32768 + (wc * 64 + fr) * 32 + colswz;  // B region at +32768

    // ---- staging: linear LDS dest, inverse-swizzled global source
    const int srow = t >> 2;                                 // 0..127
    const int sswz = (((t & 3) ^ ((srow >> 1) & 3)) << 3);   // shorts
    const short* pA0 = A + (row0 + srow) * (size_t)K_DIM + sswz;
    const short* pA1 = pA0 + (size_t)128 * K_DIM;
    const short* pB0 = B + (col0 + srow) * (size_t)K_DIM + sswz;
    const short* pB1 = pB0 + (size_t)128 * K_DIM;
    const int ldst0 = t * 8;                                 // shorts

    f32x4 acc[8][4];
#pragma unroll
    for (int m = 0; m < 8; ++m)
#pragma unroll
        for (int n = 0; n < 4; ++n) acc[m][n] = (f32x4)0.f;

    short8 af[4], bf0[4], bf1[4];

// stage one K-half slot: 2 x global_load_lds (rows srow and srow+128)
#define STG(P0, P1, SLOT, OFFB) do {                                   \
    async16(&lds[(SLOT) + ldst0], (const char*)(P0) + (OFFB));         \
    async16(&lds[(SLOT) + 4096 + ldst0], (const char*)(P1) + (OFFB));  \
} while (0)

#define RDA(KSLOT, MH) do {                                            \
    _Pragma("unroll") for (int m = 0; m < 4; ++m)                      \
        af[m] = *(const short8*)&lds[(KSLOT) + ((MH) * 4 + m) * 512 + aoff]; \
} while (0)

#define RDB(DST, KSLOT) do {                                           \
    _Pragma("unroll") for (int n = 0; n < 4; ++n)                      \
        DST[n] = *(const short8*)&lds[(KSLOT) + n * 512 + boff];       \
} while (0)

#define MFQ(BF, MH) do {                                               \
    _Pragma("unroll") for (int m = 0; m < 4; ++m)                      \
        _Pragma("unroll") for (int n = 0; n < 4; ++n)                  \
            acc[(MH) * 4 + m][n] = __builtin_amdgcn_mfma_f32_16x16x32_bf16( \
                af[m], BF[n], acc[(MH) * 4 + m][n], 0, 0, 0);          \
} while (0)

#define MMA(BF, MH) do { PRIO1(); MFQ(BF, MH); PRIO0();                \
    __builtin_amdgcn_sched_barrier(0); } while (0)

    // ---- prologue: tile0 (4 halves) + tile1 kk0 halves = 12 gll
    STG(pA0, pA1, 0,     0);    // A(0,kk0)  -> A[0][0]
    STG(pB0, pB1, 32768, 0);    // B(0,kk0)  -> B[0][0]
    STG(pA0, pA1, 8192,  64);   // A(0,kk32) -> A[0][1]
    STG(pB0, pB1, 40960, 64);   // B(0,kk32) -> B[0][1]
    STG(pA0, pA1, 16384, 128);  // A(1,kk0)  -> A[1][0]
    STG(pB0, pB1, 49152, 128);  // B(1,kk0)  -> B[1][0]
    VMC(4);                     // tile0's 4 halves landed; A10,B10 in flight
    BAR();

    // ---- main loop: 31 iterations x 2 K-tiles (tiles 0..61), 1 bar/phase
    for (int it = 0; it < 31; ++it) {
        // == tile g (even, buf 0) ==
        // ph1: kk0,mh0 | stage A(g+1,kk32) -> A[1][1]
        RDB(bf0, 0); RDA(0, 0);
        STG(pA0, pA1, 24576, 192);
        BAR(); LGKM0(); MMA(bf0, 0);
        // ph2: kk0,mh1 | stage B(g+1,kk32) -> B[1][1]
        RDA(0, 1);
        STG(pB0, pB1, 57344, 192);
        BAR(); LGKM0(); MMA(bf0, 1);
        // ph3: kk32,mh0 | stage A(g+2,kk0) -> A[0][0]
        RDB(bf1, 8192); RDA(8192, 0);
        STG(pA0, pA1, 0, 256);
        BAR(); LGKM0(); MMA(bf1, 0);
        // ph4: kk32,mh1 | stage B(g+2,kk0) -> B[0][0] | gate: tile g+1 landed
        RDA(8192, 1);
        STG(pB0, pB1, 32768, 256);
        VMC(4);
        BAR(); LGKM0(); MMA(bf1, 1);

        // == tile g+1 (odd, buf 1) ==
        // ph5: kk0,mh0 | stage A(g+2,kk32) -> A[0][1]
        RDB(bf0, 16384); RDA(16384, 0);
        STG(pA0, pA1, 8192, 320);
        BAR(); LGKM0(); MMA(bf0, 0);
        // ph6: kk0,mh1 | stage B(g+2,kk32) -> B[0][1]
        RDA(16384, 1);
        STG(pB0, pB1, 40960, 320);
        BAR(); LGKM0(); MMA(bf0, 1);
        // ph7: kk32,mh0 | stage A(g+3,kk0) -> A[1][0]
        RDB(bf1, 24576); RDA(24576, 0);
        STG(pA0, pA1, 16384, 384);
        BAR(); LGKM0(); MMA(bf1, 0);
        // ph8: kk32,mh1 | stage B(g+3,kk0) -> B[1][0] | gate: tile g+2 landed
        RDA(24576, 1);
        STG(pB0, pB1, 49152, 384);
        VMC(4);
        BAR(); LGKM0(); MMA(bf1, 1);

        pA0 += 128; pA1 += 128; pB0 += 128; pB1 += 128;  // +256 B (2 K-tiles)
    }

    // ---- tail: tiles 62 (buf 0) and 63 (buf 1)
    // ph1: stage A(63,kk32) -> A[1][1]
    RDB(bf0, 0); RDA(0, 0);
    STG(pA0, pA1, 24576, 192);
    BAR(); LGKM0(); MMA(bf0, 0);
    // ph2: stage B(63,kk32) -> B[1][1]
    RDA(0, 1);
    STG(pB0, pB1, 57344, 192);
    BAR(); LGKM0(); MMA(bf0, 1);
    // ph3
    RDB(bf1, 8192); RDA(8192, 0);
    BAR(); LGKM0(); MMA(bf1, 0);
    // ph4: drain everything (tile 63's 4 halves all landed)
    RDA(8192, 1);
    VMC(0);
    BAR(); LGKM0(); MMA(bf1, 1);
    // tile 63, no stages/gates
    RDB(bf0, 16384); RDA(16384, 0);
    BAR(); LGKM0(); MMA(bf0, 0);
    RDA(16384, 1);
    BAR(); LGKM0(); MMA(bf0, 1);
    RDB(bf1, 24576); RDA(24576, 0);
    BAR(); LGKM0(); MMA(bf1, 0);
    RDA(24576, 1);
    BAR(); LGKM0(); MMA(bf1, 1);

    // ---- epilogue: C/D layout col = lane&15, row = (lane>>4)*4 + j
#pragma unroll
    for (int m = 0; m < 8; ++m) {
#pragma unroll
        for (int n = 0; n < 4; ++n) {
            f32x4 v = acc[m][n];
            long r0 = row0 + wr * 128 + m * 16 + fq * 4;
            long cc = col0 + wc * 64 + n * 16 + fr;
#pragma unroll
            for (int jj = 0; jj < 4; ++jj)
                C[(size_t)(r0 + jj) * N_DIM + cc] = v[jj];
        }
    }
#undef STG
#undef RDA
#undef RDB
#undef MFQ
#undef MMA
}

// ---------------------------------------------------------------------------
extern "C" void kernel_launch(void* const* d_in, const int* in_sizes, int n_in,
                              void* d_out, int out_size, void* d_ws, size_t ws_size,
                              hipStream_t stream) {
    const float* x  = (const float*)d_in[0];
    const int*   qw = (const int*)d_in[1];
    const float* u  = (const float*)d_in[2];
    const float* vt = (const float*)d_in[3];
    float* out = (float*)d_out;

    const size_t wb_bytes = (size_t)OUT_F * IN_F * 2;
    short* wb = (short*)d_ws;
    short* xb = (short*)((char*)d_ws + wb_bytes);

    (void)hipFuncSetAttribute((const void*)gemm256_kernel,
                              hipFuncAttributeMaxDynamicSharedMemorySize, 131072);

    hipLaunchKernelGGL(convert_x_kernel, dim3(2048), dim3(256), 0, stream, x, xb);
    hipLaunchKernelGGL(reconstruct_w_kernel, dim3(IN_F / 128, OUT_F / 64), dim3(256), 0, stream,
                       qw, u, vt, wb);
    hipLaunchKernelGGL(gemm256_kernel, dim3((M_DIM / 256) * (N_DIM / 256)), dim3(512), 131072,
                       stream, xb, wb, out);
}

// Round 10
// 875.531 us; speedup vs baseline: 1.2787x; 1.0071x over previous
//
#include <hip/hip_runtime.h>
#include <hip/hip_bf16.h>

#define W_BIT 4
#define OUT_F 11008
#define IN_F 4096
#define KRANK 16
#define M_DIM 8192
#define QW_PLANE (OUT_F * IN_F / 8)

#define N_DIM OUT_F
#define K_DIM 4096
#define NT 64              // K tiles of 64
#define NBN 43             // N_DIM / 256

typedef __attribute__((ext_vector_type(8))) short short8;
typedef __attribute__((ext_vector_type(4))) float f32x4;

__device__ __forceinline__ short f2bf(float f) {
    union { float f; unsigned u; } v;
    v.f = f;
    unsigned r = v.u + 0x7fffu + ((v.u >> 16) & 1u);
    return (short)(r >> 16);
}

__device__ __forceinline__ void async16(void* lds_p, const void* g) {
    __builtin_amdgcn_global_load_lds(
        (const __attribute__((address_space(1))) unsigned int*)g,
        (__attribute__((address_space(3))) unsigned int*)lds_p,
        16, 0, 0);
}

#define BAR() __builtin_amdgcn_s_barrier()
#define LGKM(n) do { asm volatile("s_waitcnt lgkmcnt(" #n ")" ::: "memory"); \
                     __builtin_amdgcn_sched_barrier(0); } while (0)
#define VMC(n) do { asm volatile("s_waitcnt vmcnt(" #n ")" ::: "memory"); \
                    __builtin_amdgcn_sched_barrier(0); } while (0)
#define PRIO1() __builtin_amdgcn_s_setprio(1)
#define PRIO0() __builtin_amdgcn_s_setprio(0)

// volatile asm ds_read_b128: issue order is pinned -> counted lgkm is exact
#define DSR(DST, AV, IMM) \
    asm volatile("ds_read_b128 %0, %1 offset:%2" : "=v"(DST) : "v"(AV), "n"(IMM))

// ---------------------------------------------------------------------------
// Kernel 1: x fp32 -> bf16
// ---------------------------------------------------------------------------
__global__ __launch_bounds__(256) void convert_x_kernel(
    const float* __restrict__ x, short* __restrict__ xb) {
    int tid = blockIdx.x * blockDim.x + threadIdx.x;
    int stride = gridDim.x * blockDim.x;
    const int n8 = (M_DIM * IN_F) / 8;
    for (int i = tid; i < n8; i += stride) {
        f32x4 a = ((const f32x4*)x)[2 * i];
        f32x4 b = ((const f32x4*)x)[2 * i + 1];
        short8 o;
        o[0] = f2bf(a[0]); o[1] = f2bf(a[1]); o[2] = f2bf(a[2]); o[3] = f2bf(a[3]);
        o[4] = f2bf(b[0]); o[5] = f2bf(b[1]); o[6] = f2bf(b[2]); o[7] = f2bf(b[3]);
        ((short8*)xb)[i] = o;
    }
}

// ---------------------------------------------------------------------------
// Kernel 2: reconstruct w (unchanged from passing rounds)
// ---------------------------------------------------------------------------
__global__ __launch_bounds__(256) void reconstruct_w_kernel(
    const int* __restrict__ qw, const float* __restrict__ u,
    const float* __restrict__ vt, short* __restrict__ wb) {
    __shared__ float vts[W_BIT][KRANK][128];
    __shared__ float us[W_BIT][KRANK][64];

    const int t = threadIdx.x;
    const int o0 = blockIdx.y * 64;
    const int c0 = blockIdx.x * 128;

    for (int idx = t; idx < W_BIT * KRANK * 128; idx += 256) {
        int i = idx >> 11, rem = idx & 2047, k = rem >> 7, c = rem & 127;
        vts[i][k][c] = vt[(i * KRANK + k) * IN_F + c0 + c];
    }
    for (int idx = t; idx < W_BIT * KRANK * 64; idx += 256) {
        int i = idx >> 10, rem = idx & 1023, o = rem >> 4, k = rem & 15;
        us[i][k][o] = u[((size_t)i * OUT_F + o0 + o) * KRANK + k];
    }
    __syncthreads();

    const int to = (t >> 4) * 4;
    const int tc = (t & 15) * 8;

    float wacc[4][8];
#pragma unroll
    for (int r = 0; r < 4; ++r)
#pragma unroll
        for (int c = 0; c < 8; ++c) wacc[r][c] = 0.f;

#pragma unroll
    for (int i = 0; i < W_BIT; ++i) {
        float dot[4][8];
#pragma unroll
        for (int r = 0; r < 4; ++r)
#pragma unroll
            for (int c = 0; c < 8; ++c) dot[r][c] = 0.f;
#pragma unroll
        for (int k = 0; k < KRANK; ++k) {
            f32x4 uv = *(const f32x4*)&us[i][k][to];
            f32x4 v0 = *(const f32x4*)&vts[i][k][tc];
            f32x4 v1 = *(const f32x4*)&vts[i][k][tc + 4];
#pragma unroll
            for (int r = 0; r < 4; ++r) {
#pragma unroll
                for (int c = 0; c < 4; ++c) {
                    dot[r][c]     += uv[r] * v0[c];
                    dot[r][c + 4] += uv[r] * v1[c];
                }
            }
        }
#pragma unroll
        for (int r = 0; r < 4; ++r) {
            unsigned byte = (unsigned)qw[i * QW_PLANE + (((o0 + to + r) * IN_F + c0 + tc) >> 3)];
#pragma unroll
            for (int c = 0; c < 8; ++c)
                wacc[r][c] += ((byte >> c) & 1u) ? dot[r][c] : -dot[r][c];
        }
    }
#pragma unroll
    for (int r = 0; r < 4; ++r) {
        short8 o8;
#pragma unroll
        for (int c = 0; c < 8; ++c) o8[c] = f2bf(wacc[r][c]);
        *(short8*)&wb[(size_t)(o0 + to + r) * IN_F + c0 + tc] = o8;
    }
}

// ---------------------------------------------------------------------------
// Kernel 3: R8 skeleton (1 barrier/phase, vmcnt(4) gates at ph4/ph8) +
// one-phase-ahead fragment reads in ping-pong register sets with counted
// lgkmcnt -- now with ALL fragment reads as volatile inline-asm ds_read_b128
// (issue order pinned, so the counted waits are exact; plain C++ loads were
// compiler-reordered in R9 -> NaN). Geometry: 256x256 tile, BK=64, 8 waves
// (2x4), K-half slots [256r][32k], granule-XOR swizzle (0 bank conflicts),
// 2 global_load_lds staged per phase.
// ---------------------------------------------------------------------------
__global__ __launch_bounds__(512, 2) void gemm256_kernel(
    const short* __restrict__ A, const short* __restrict__ B, float* __restrict__ C) {
    extern __shared__ short lds[];

    const int t = threadIdx.x;
    const int lane = t & 63, wid = t >> 6;
    const int wr = wid >> 2, wc = wid & 3;       // 2 x 4 wave grid
    const int fr = lane & 15, fq = lane >> 4;

    const int bid = blockIdx.x;
    const int cpx = gridDim.x >> 3;              // grid 1376 % 8 == 0
    const int swzb = (bid & 7) * cpx + (bid >> 3);
    const int bm = swzb / NBN, bn = swzb % NBN;
    const long row0 = (long)bm * 256, col0 = (long)bn * 256;

    // ---- fragment read bases (granule-XOR swizzle, lane-constant)
    const int colswz = (fq ^ ((fr >> 1) & 3)) * 8;          // shorts in 32-col row
    const int aoff = (wr * 128 + fr) * 32 + colswz;         // A region at 0
    const int boff = 32768 + (wc * 64 + fr) * 32 + colswz;  // B region at +32768

    // 32-bit LDS byte addresses for asm ds_read
    const unsigned av = (unsigned)(size_t)((__attribute__((address_space(3))) short*)lds + aoff);
    const unsigned bv = (unsigned)(size_t)((__attribute__((address_space(3))) short*)lds + boff);

    // ---- staging: linear LDS dest, inverse-swizzled global source
    const int srow = t >> 2;                                 // 0..127
    const int sswz = (((t & 3) ^ ((srow >> 1) & 3)) << 3);   // shorts
    const short* pA0 = A + (row0 + srow) * (size_t)K_DIM + sswz;
    const short* pA1 = pA0 + (size_t)128 * K_DIM;
    const short* pB0 = B + (col0 + srow) * (size_t)K_DIM + sswz;
    const short* pB1 = pB0 + (size_t)128 * K_DIM;
    const int ldst0 = t * 8;                                 // shorts

    f32x4 acc[8][4];
#pragma unroll
    for (int m = 0; m < 8; ++m)
#pragma unroll
        for (int n = 0; n < 4; ++n) acc[m][n] = (f32x4)0.f;

    short8 afA[4], afB[4], bf0[4], bf1[4];

// stage one K-half slot: 2 x global_load_lds (rows srow and srow+128)
#define STG(P0, P1, SLOT, OFFB) do {                                   \
    async16(&lds[(SLOT) + ldst0], (const char*)(P0) + (OFFB));         \
    async16(&lds[(SLOT) + 4096 + ldst0], (const char*)(P1) + (OFFB));  \
} while (0)

// A-fragment reads (4 x asm ds_read_b128); KSLOT/MH literal macro args
#define RDA(SET, KSLOT, MH) do {                                       \
    DSR(SET[0], av, ((KSLOT) + ((MH) * 4 + 0) * 512) * 2);             \
    DSR(SET[1], av, ((KSLOT) + ((MH) * 4 + 1) * 512) * 2);             \
    DSR(SET[2], av, ((KSLOT) + ((MH) * 4 + 2) * 512) * 2);             \
    DSR(SET[3], av, ((KSLOT) + ((MH) * 4 + 3) * 512) * 2);             \
} while (0)

// B-fragment reads; KSLOT absolute (>= 32768), folded into immediate
#define RDB(DST, KSLOT) do {                                           \
    DSR(DST[0], bv, ((KSLOT) - 32768 + 0 * 512) * 2);                  \
    DSR(DST[1], bv, ((KSLOT) - 32768 + 1 * 512) * 2);                  \
    DSR(DST[2], bv, ((KSLOT) - 32768 + 2 * 512) * 2);                  \
    DSR(DST[3], bv, ((KSLOT) - 32768 + 3 * 512) * 2);                  \
} while (0)

#define MMA(AF, BF, MH) do { PRIO1();                                  \
    _Pragma("unroll") for (int m = 0; m < 4; ++m)                      \
        _Pragma("unroll") for (int n = 0; n < 4; ++n)                  \
            acc[(MH) * 4 + m][n] = __builtin_amdgcn_mfma_f32_16x16x32_bf16( \
                AF[m], BF[n], acc[(MH) * 4 + m][n], 0, 0, 0);          \
    PRIO0(); __builtin_amdgcn_sched_barrier(0); } while (0)

    // ---- prologue: tile0 (4 halves) + tile1 kk0 halves = 12 gll
    STG(pA0, pA1, 0,     0);    // A(0,kk0)  -> A[0][0]
    STG(pB0, pB1, 32768, 0);    // B(0,kk0)  -> B[0][0]
    STG(pA0, pA1, 8192,  64);   // A(0,kk32) -> A[0][1]
    STG(pB0, pB1, 40960, 64);   // B(0,kk32) -> B[0][1]
    STG(pA0, pA1, 16384, 128);  // A(1,kk0)  -> A[1][0]
    STG(pB0, pB1, 49152, 128);  // B(1,kk0)  -> B[1][0]
    VMC(4);                     // tile0's 4 halves landed; A10,B10 in flight
    BAR();
    // pre-issue ph1 consumables (tile0 kk0: afA mh0, bf0)
    RDA(afA, 0, 0); RDB(bf0, 32768);

    // ---- main loop: 31 iterations x 2 K-tiles (tiles 0..61)
    for (int it = 0; it < 31; ++it) {
        // == tile g (even, buf 0) ==
        // ph1: MFMA kk0xmh0 | issue afB(kk0,mh1) | stage A(g+1,kk32)
        RDA(afB, 0, 1);
        STG(pA0, pA1, 24576, 192);
        BAR(); LGKM(4); MMA(afA, bf0, 0);
        // ph2: MFMA kk0xmh1 | issue bf1(kk32)+afA(kk32,mh0) | stage B(g+1,kk32)
        RDB(bf1, 40960); RDA(afA, 8192, 0);
        STG(pB0, pB1, 57344, 192);
        BAR(); LGKM(8); MMA(afB, bf0, 1);
        // ph3: MFMA kk32xmh0 | issue afB(kk32,mh1) | stage A(g+2,kk0)
        RDA(afB, 8192, 1);
        STG(pA0, pA1, 0, 256);
        BAR(); LGKM(4); MMA(afA, bf1, 0);
        // ph4: MFMA kk32xmh1 | stage B(g+2,kk0) | gate | issue next-tile kk0
        STG(pB0, pB1, 32768, 256);
        VMC(4);
        RDB(bf0, 49152); RDA(afA, 16384, 0);
        BAR(); LGKM(8); MMA(afB, bf1, 1);

        // == tile g+1 (odd, buf 1) ==
        // ph5
        RDA(afB, 16384, 1);
        STG(pA0, pA1, 8192, 320);
        BAR(); LGKM(4); MMA(afA, bf0, 0);
        // ph6
        RDB(bf1, 57344); RDA(afA, 24576, 0);
        STG(pB0, pB1, 40960, 320);
        BAR(); LGKM(8); MMA(afB, bf0, 1);
        // ph7
        RDA(afB, 24576, 1);
        STG(pA0, pA1, 16384, 384);
        BAR(); LGKM(4); MMA(afA, bf1, 0);
        // ph8: stage B(g+3,kk0) | gate | issue next-even-tile kk0
        STG(pB0, pB1, 49152, 384);
        VMC(4);
        RDB(bf0, 32768); RDA(afA, 0, 0);
        BAR(); LGKM(8); MMA(afB, bf1, 1);

        pA0 += 128; pA1 += 128; pB0 += 128; pB1 += 128;  // +256 B (2 K-tiles)
    }

    // ---- tail: tiles 62 (buf 0) and 63 (buf 1)
    // ph1t: stage A(63,kk32)
    RDA(afB, 0, 1);
    STG(pA0, pA1, 24576, 192);
    BAR(); LGKM(4); MMA(afA, bf0, 0);
    // ph2t: stage B(63,kk32)
    RDB(bf1, 40960); RDA(afA, 8192, 0);
    STG(pB0, pB1, 57344, 192);
    BAR(); LGKM(8); MMA(afB, bf0, 1);
    // ph3t
    RDA(afB, 8192, 1);
    BAR(); LGKM(4); MMA(afA, bf1, 0);
    // ph4t: drain all staging (tile 63's 4 halves landed), issue tile63 kk0
    VMC(0);
    RDB(bf0, 49152); RDA(afA, 16384, 0);
    BAR(); LGKM(8); MMA(afB, bf1, 1);
    // ph5t
    RDA(afB, 16384, 1);
    BAR(); LGKM(4); MMA(afA, bf0, 0);
    // ph6t
    RDB(bf1, 57344); RDA(afA, 24576, 0);
    BAR(); LGKM(8); MMA(afB, bf0, 1);
    // ph7t
    RDA(afB, 24576, 1);
    BAR(); LGKM(4); MMA(afA, bf1, 0);
    // ph8t
    BAR(); LGKM(0); MMA(afB, bf1, 1);

    // ---- epilogue: C/D layout col = lane&15, row = (lane>>4)*4 + j
#pragma unroll
    for (int m = 0; m < 8; ++m) {
#pragma unroll
        for (int n = 0; n < 4; ++n) {
            f32x4 v = acc[m][n];
            long r0 = row0 + wr * 128 + m * 16 + fq * 4;
            long cc = col0 + wc * 64 + n * 16 + fr;
#pragma unroll
            for (int jj = 0; jj < 4; ++jj)
                C[(size_t)(r0 + jj) * N_DIM + cc] = v[jj];
        }
    }
#undef STG
#undef RDA
#undef RDB
#undef MMA
}

// ---------------------------------------------------------------------------
extern "C" void kernel_launch(void* const* d_in, const int* in_sizes, int n_in,
                              void* d_out, int out_size, void* d_ws, size_t ws_size,
                              hipStream_t stream) {
    const float* x  = (const float*)d_in[0];
    const int*   qw = (const int*)d_in[1];
    const float* u  = (const float*)d_in[2];
    const float* vt = (const float*)d_in[3];
    float* out = (float*)d_out;

    const size_t wb_bytes = (size_t)OUT_F * IN_F * 2;
    short* wb = (short*)d_ws;
    short* xb = (short*)((char*)d_ws + wb_bytes);

    (void)hipFuncSetAttribute((const void*)gemm256_kernel,
                              hipFuncAttributeMaxDynamicSharedMemorySize, 131072);

    hipLaunchKernelGGL(convert_x_kernel, dim3(2048), dim3(256), 0, stream, x, xb);
    hipLaunchKernelGGL(reconstruct_w_kernel, dim3(IN_F / 128, OUT_F / 64), dim3(256), 0, stream,
                       qw, u, vt, wb);
    hipLaunchKernelGGL(gemm256_kernel, dim3((M_DIM / 256) * (N_DIM / 256)), dim3(512), 131072,
                       stream, xb, wb, out);
}

// Round 11
// 855.896 us; speedup vs baseline: 1.3080x; 1.0229x over previous
//
#include <hip/hip_runtime.h>
#include <hip/hip_bf16.h>

#define W_BIT 4
#define OUT_F 11008
#define IN_F 4096
#define KRANK 16
#define M_DIM 8192
#define QW_PLANE (OUT_F * IN_F / 8)

#define N_DIM OUT_F
#define K_DIM 4096
#define NT 64              // K tiles of 64
#define NBN 43             // N_DIM / 256
#define RW_BLOCKS 5504     // (IN_F/128) * (OUT_F/64)
#define CV_BLOCKS 1024

typedef __attribute__((ext_vector_type(8))) short short8;
typedef __attribute__((ext_vector_type(4))) float f32x4;

__device__ __forceinline__ short f2bf(float f) {
    union { float f; unsigned u; } v;
    v.f = f;
    unsigned r = v.u + 0x7fffu + ((v.u >> 16) & 1u);
    return (short)(r >> 16);
}

__device__ __forceinline__ void async16(void* lds_p, const void* g) {
    __builtin_amdgcn_global_load_lds(
        (const __attribute__((address_space(1))) unsigned int*)g,
        (__attribute__((address_space(3))) unsigned int*)lds_p,
        16, 0, 0);
}

#define BAR() __builtin_amdgcn_s_barrier()
#define LGKM(n) do { asm volatile("s_waitcnt lgkmcnt(" #n ")" ::: "memory"); \
                     __builtin_amdgcn_sched_barrier(0); } while (0)
#define VMC(n) do { asm volatile("s_waitcnt vmcnt(" #n ")" ::: "memory"); \
                    __builtin_amdgcn_sched_barrier(0); } while (0)
#define PRIO1() __builtin_amdgcn_s_setprio(1)
#define PRIO0() __builtin_amdgcn_s_setprio(0)

// volatile asm ds_read_b128: issue order is pinned -> counted lgkm is exact
#define DSR(DST, AV, IMM) \
    asm volatile("ds_read_b128 %0, %1 offset:%2" : "=v"(DST) : "v"(AV), "n"(IMM))

// ---------------------------------------------------------------------------
// Fused prep: blocks [0, RW_BLOCKS) reconstruct w (div-free float4 staging);
// blocks [RW_BLOCKS, RW_BLOCKS+CV_BLOCKS) convert x -> bf16.
// ---------------------------------------------------------------------------
__global__ __launch_bounds__(256) void prep_kernel(
    const float* __restrict__ x, const int* __restrict__ qw,
    const float* __restrict__ u, const float* __restrict__ vt,
    short* __restrict__ xb, short* __restrict__ wb) {
    const int b = blockIdx.x;
    const int t = threadIdx.x;

    if (b >= RW_BLOCKS) {
        // ---- convert x (grid-stride, float4 in / short8 out)
        const int n8 = (M_DIM * IN_F) / 8;
        int tid = (b - RW_BLOCKS) * 256 + t;
        for (int i = tid; i < n8; i += CV_BLOCKS * 256) {
            f32x4 a = ((const f32x4*)x)[2 * i];
            f32x4 c = ((const f32x4*)x)[2 * i + 1];
            short8 o;
            o[0] = f2bf(a[0]); o[1] = f2bf(a[1]); o[2] = f2bf(a[2]); o[3] = f2bf(a[3]);
            o[4] = f2bf(c[0]); o[5] = f2bf(c[1]); o[6] = f2bf(c[2]); o[7] = f2bf(c[3]);
            ((short8*)xb)[i] = o;
        }
        return;
    }

    // ---- reconstruct w: tile 64 o-rows x 128 in-cols
    __shared__ float vts[64][128];   // [i*16+k][c]  32 KB
    __shared__ float us[64][64];     // [i*16+k][o]  16 KB

    const int c0 = (b & 31) * 128;
    const int o0 = (b >> 5) * 64;

    // stage vt: 64 rows x 32 float4, div-free (8 float4 per thread)
    {
        const f32x4* vt4 = (const f32x4*)vt;     // row length 1024 quads
        const int l32 = t & 31;
        const int r0w = t >> 5;                   // 0..7
#pragma unroll
        for (int j = 0; j < 8; ++j) {
            int row = r0w + j * 8;                // 0..63 = i*16+k
            ((f32x4*)&vts[row][0])[l32] = vt4[(size_t)row * 1024 + (c0 >> 2) + l32];
        }
    }
    // stage u transposed: u[i][o][k] -> us[i*16+k][o] (4 float4 per thread)
    {
        const int o = t & 63, q = t >> 6;         // q: 0..3 (k-quad)
#pragma unroll
        for (int i = 0; i < 4; ++i) {
            f32x4 v = ((const f32x4*)u)[((size_t)i * OUT_F + o0 + o) * 4 + q];
            us[i * 16 + q * 4 + 0][o] = v[0];
            us[i * 16 + q * 4 + 1][o] = v[1];
            us[i * 16 + q * 4 + 2][o] = v[2];
            us[i * 16 + q * 4 + 3][o] = v[3];
        }
    }
    __syncthreads();

    const int to = (t >> 4) * 4;
    const int tc = (t & 15) * 8;

    float wacc[4][8];
#pragma unroll
    for (int r = 0; r < 4; ++r)
#pragma unroll
        for (int c = 0; c < 8; ++c) wacc[r][c] = 0.f;

#pragma unroll
    for (int i = 0; i < W_BIT; ++i) {
        float dot[4][8];
#pragma unroll
        for (int r = 0; r < 4; ++r)
#pragma unroll
            for (int c = 0; c < 8; ++c) dot[r][c] = 0.f;
#pragma unroll
        for (int k = 0; k < KRANK; ++k) {
            f32x4 uv = *(const f32x4*)&us[i * 16 + k][to];
            f32x4 v0 = *(const f32x4*)&vts[i * 16 + k][tc];
            f32x4 v1 = *(const f32x4*)&vts[i * 16 + k][tc + 4];
#pragma unroll
            for (int r = 0; r < 4; ++r) {
#pragma unroll
                for (int c = 0; c < 4; ++c) {
                    dot[r][c]     += uv[r] * v0[c];
                    dot[r][c + 4] += uv[r] * v1[c];
                }
            }
        }
#pragma unroll
        for (int r = 0; r < 4; ++r) {
            unsigned byte = (unsigned)qw[i * QW_PLANE + (((o0 + to + r) * IN_F + c0 + tc) >> 3)];
#pragma unroll
            for (int c = 0; c < 8; ++c)
                wacc[r][c] += ((byte >> c) & 1u) ? dot[r][c] : -dot[r][c];
        }
    }
#pragma unroll
    for (int r = 0; r < 4; ++r) {
        short8 o8;
#pragma unroll
        for (int c = 0; c < 8; ++c) o8[c] = f2bf(wacc[r][c]);
        *(short8*)&wb[(size_t)(o0 + to + r) * IN_F + c0 + tc] = o8;
    }
}

// ---------------------------------------------------------------------------
// Kernel 3: unchanged from R10 (best passing GEMM): 256x256 tile, BK=64,
// 8 waves (2x4), 1 barrier/phase, vmcnt(4) gates at ph4/ph8, one-phase-ahead
// asm ds_read_b128 fragment reads with counted lgkmcnt, granule-XOR swizzle.
// ---------------------------------------------------------------------------
__global__ __launch_bounds__(512, 2) void gemm256_kernel(
    const short* __restrict__ A, const short* __restrict__ B, float* __restrict__ C) {
    extern __shared__ short lds[];

    const int t = threadIdx.x;
    const int lane = t & 63, wid = t >> 6;
    const int wr = wid >> 2, wc = wid & 3;       // 2 x 4 wave grid
    const int fr = lane & 15, fq = lane >> 4;

    const int bid = blockIdx.x;
    const int cpx = gridDim.x >> 3;              // grid 1376 % 8 == 0
    const int swzb = (bid & 7) * cpx + (bid >> 3);
    const int bm = swzb / NBN, bn = swzb % NBN;
    const long row0 = (long)bm * 256, col0 = (long)bn * 256;

    // ---- fragment read bases (granule-XOR swizzle, lane-constant)
    const int colswz = (fq ^ ((fr >> 1) & 3)) * 8;          // shorts in 32-col row
    const int aoff = (wr * 128 + fr) * 32 + colswz;         // A region at 0
    const int boff = 32768 + (wc * 64 + fr) * 32 + colswz;  // B region at +32768

    // 32-bit LDS byte addresses for asm ds_read
    const unsigned av = (unsigned)(size_t)((__attribute__((address_space(3))) short*)lds + aoff);
    const unsigned bv = (unsigned)(size_t)((__attribute__((address_space(3))) short*)lds + boff);

    // ---- staging: linear LDS dest, inverse-swizzled global source
    const int srow = t >> 2;                                 // 0..127
    const int sswz = (((t & 3) ^ ((srow >> 1) & 3)) << 3);   // shorts
    const short* pA0 = A + (row0 + srow) * (size_t)K_DIM + sswz;
    const short* pA1 = pA0 + (size_t)128 * K_DIM;
    const short* pB0 = B + (col0 + srow) * (size_t)K_DIM + sswz;
    const short* pB1 = pB0 + (size_t)128 * K_DIM;
    const int ldst0 = t * 8;                                 // shorts

    f32x4 acc[8][4];
#pragma unroll
    for (int m = 0; m < 8; ++m)
#pragma unroll
        for (int n = 0; n < 4; ++n) acc[m][n] = (f32x4)0.f;

    short8 afA[4], afB[4], bf0[4], bf1[4];

#define STG(P0, P1, SLOT, OFFB) do {                                   \
    async16(&lds[(SLOT) + ldst0], (const char*)(P0) + (OFFB));         \
    async16(&lds[(SLOT) + 4096 + ldst0], (const char*)(P1) + (OFFB));  \
} while (0)

#define RDA(SET, KSLOT, MH) do {                                       \
    DSR(SET[0], av, ((KSLOT) + ((MH) * 4 + 0) * 512) * 2);             \
    DSR(SET[1], av, ((KSLOT) + ((MH) * 4 + 1) * 512) * 2);             \
    DSR(SET[2], av, ((KSLOT) + ((MH) * 4 + 2) * 512) * 2);             \
    DSR(SET[3], av, ((KSLOT) + ((MH) * 4 + 3) * 512) * 2);             \
} while (0)

#define RDB(DST, KSLOT) do {                                           \
    DSR(DST[0], bv, ((KSLOT) - 32768 + 0 * 512) * 2);                  \
    DSR(DST[1], bv, ((KSLOT) - 32768 + 1 * 512) * 2);                  \
    DSR(DST[2], bv, ((KSLOT) - 32768 + 2 * 512) * 2);                  \
    DSR(DST[3], bv, ((KSLOT) - 32768 + 3 * 512) * 2);                  \
} while (0)

#define MMA(AF, BF, MH) do { PRIO1();                                  \
    _Pragma("unroll") for (int m = 0; m < 4; ++m)                      \
        _Pragma("unroll") for (int n = 0; n < 4; ++n)                  \
            acc[(MH) * 4 + m][n] = __builtin_amdgcn_mfma_f32_16x16x32_bf16( \
                AF[m], BF[n], acc[(MH) * 4 + m][n], 0, 0, 0);          \
    PRIO0(); __builtin_amdgcn_sched_barrier(0); } while (0)

    // ---- prologue: tile0 (4 halves) + tile1 kk0 halves = 12 gll
    STG(pA0, pA1, 0,     0);    // A(0,kk0)  -> A[0][0]
    STG(pB0, pB1, 32768, 0);    // B(0,kk0)  -> B[0][0]
    STG(pA0, pA1, 8192,  64);   // A(0,kk32) -> A[0][1]
    STG(pB0, pB1, 40960, 64);   // B(0,kk32) -> B[0][1]
    STG(pA0, pA1, 16384, 128);  // A(1,kk0)  -> A[1][0]
    STG(pB0, pB1, 49152, 128);  // B(1,kk0)  -> B[1][0]
    VMC(4);                     // tile0's 4 halves landed; A10,B10 in flight
    BAR();
    RDA(afA, 0, 0); RDB(bf0, 32768);

    // ---- main loop: 31 iterations x 2 K-tiles (tiles 0..61)
    for (int it = 0; it < 31; ++it) {
        // == tile g (even, buf 0) ==
        RDA(afB, 0, 1);
        STG(pA0, pA1, 24576, 192);
        BAR(); LGKM(4); MMA(afA, bf0, 0);
        RDB(bf1, 40960); RDA(afA, 8192, 0);
        STG(pB0, pB1, 57344, 192);
        BAR(); LGKM(8); MMA(afB, bf0, 1);
        RDA(afB, 8192, 1);
        STG(pA0, pA1, 0, 256);
        BAR(); LGKM(4); MMA(afA, bf1, 0);
        STG(pB0, pB1, 32768, 256);
        VMC(4);
        RDB(bf0, 49152); RDA(afA, 16384, 0);
        BAR(); LGKM(8); MMA(afB, bf1, 1);

        // == tile g+1 (odd, buf 1) ==
        RDA(afB, 16384, 1);
        STG(pA0, pA1, 8192, 320);
        BAR(); LGKM(4); MMA(afA, bf0, 0);
        RDB(bf1, 57344); RDA(afA, 24576, 0);
        STG(pB0, pB1, 40960, 320);
        BAR(); LGKM(8); MMA(afB, bf0, 1);
        RDA(afB, 24576, 1);
        STG(pA0, pA1, 16384, 384);
        BAR(); LGKM(4); MMA(afA, bf1, 0);
        STG(pB0, pB1, 49152, 384);
        VMC(4);
        RDB(bf0, 32768); RDA(afA, 0, 0);
        BAR(); LGKM(8); MMA(afB, bf1, 1);

        pA0 += 128; pA1 += 128; pB0 += 128; pB1 += 128;  // +256 B (2 K-tiles)
    }

    // ---- tail: tiles 62 (buf 0) and 63 (buf 1)
    RDA(afB, 0, 1);
    STG(pA0, pA1, 24576, 192);
    BAR(); LGKM(4); MMA(afA, bf0, 0);
    RDB(bf1, 40960); RDA(afA, 8192, 0);
    STG(pB0, pB1, 57344, 192);
    BAR(); LGKM(8); MMA(afB, bf0, 1);
    RDA(afB, 8192, 1);
    BAR(); LGKM(4); MMA(afA, bf1, 0);
    VMC(0);
    RDB(bf0, 49152); RDA(afA, 16384, 0);
    BAR(); LGKM(8); MMA(afB, bf1, 1);
    RDA(afB, 16384, 1);
    BAR(); LGKM(4); MMA(afA, bf0, 0);
    RDB(bf1, 57344); RDA(afA, 24576, 0);
    BAR(); LGKM(8); MMA(afB, bf0, 1);
    RDA(afB, 24576, 1);
    BAR(); LGKM(4); MMA(afA, bf1, 0);
    BAR(); LGKM(0); MMA(afB, bf1, 1);

    // ---- epilogue: C/D layout col = lane&15, row = (lane>>4)*4 + j
#pragma unroll
    for (int m = 0; m < 8; ++m) {
#pragma unroll
        for (int n = 0; n < 4; ++n) {
            f32x4 v = acc[m][n];
            long r0 = row0 + wr * 128 + m * 16 + fq * 4;
            long cc = col0 + wc * 64 + n * 16 + fr;
#pragma unroll
            for (int jj = 0; jj < 4; ++jj)
                C[(size_t)(r0 + jj) * N_DIM + cc] = v[jj];
        }
    }
#undef STG
#undef RDA
#undef RDB
#undef MMA
}

// ---------------------------------------------------------------------------
extern "C" void kernel_launch(void* const* d_in, const int* in_sizes, int n_in,
                              void* d_out, int out_size, void* d_ws, size_t ws_size,
                              hipStream_t stream) {
    const float* x  = (const float*)d_in[0];
    const int*   qw = (const int*)d_in[1];
    const float* u  = (const float*)d_in[2];
    const float* vt = (const float*)d_in[3];
    float* out = (float*)d_out;

    const size_t wb_bytes = (size_t)OUT_F * IN_F * 2;
    short* wb = (short*)d_ws;
    short* xb = (short*)((char*)d_ws + wb_bytes);

    (void)hipFuncSetAttribute((const void*)gemm256_kernel,
                              hipFuncAttributeMaxDynamicSharedMemorySize, 131072);

    hipLaunchKernelGGL(prep_kernel, dim3(RW_BLOCKS + CV_BLOCKS), dim3(256), 0, stream,
                       x, qw, u, vt, xb, wb);
    hipLaunchKernelGGL(gemm256_kernel, dim3((M_DIM / 256) * (N_DIM / 256)), dim3(512), 131072,
                       stream, xb, wb, out);
}

// Round 13
// 822.219 us; speedup vs baseline: 1.3616x; 1.0410x over previous
//
#include <hip/hip_runtime.h>
#include <hip/hip_bf16.h>

#define W_BIT 4
#define OUT_F 11008
#define IN_F 4096
#define KRANK 16
#define M_DIM 8192
#define QW_PLANE (OUT_F * IN_F / 8)

#define N_DIM OUT_F
#define K_DIM 4096
#define NBN 43             // N_DIM / 256
#define RW_BLOCKS 5504
#define CV_BLOCKS 1024

typedef __attribute__((ext_vector_type(8))) short short8;
typedef __attribute__((ext_vector_type(4))) float f32x4;

__device__ __forceinline__ short f2bf(float f) {
    union { float f; unsigned u; } v;
    v.f = f;
    unsigned r = v.u + 0x7fffu + ((v.u >> 16) & 1u);
    return (short)(r >> 16);
}

__device__ __forceinline__ void async16(void* lds_p, const void* g) {
    __builtin_amdgcn_global_load_lds(
        (const __attribute__((address_space(1))) unsigned int*)g,
        (__attribute__((address_space(3))) unsigned int*)lds_p,
        16, 0, 0);
}

#define BAR() __builtin_amdgcn_s_barrier()
#define LGKM0() do { asm volatile("s_waitcnt lgkmcnt(0)" ::: "memory"); \
                     __builtin_amdgcn_sched_barrier(0); } while (0)
#define VMC(n) do { asm volatile("s_waitcnt vmcnt(" #n ")" ::: "memory"); \
                    __builtin_amdgcn_sched_barrier(0); } while (0)
#define PRIO1() __builtin_amdgcn_s_setprio(1)
#define PRIO0() __builtin_amdgcn_s_setprio(0)

// volatile asm ds_read_b128: issue order pinned; byte-imm offset
#define DSR(DST, AV, IMM) \
    asm volatile("ds_read_b128 %0, %1 offset:%2" : "=v"(DST) : "v"(AV), "n"(IMM))

// ---------------------------------------------------------------------------
// Fused prep (unchanged, passing): reconstruct w + convert x.
// ---------------------------------------------------------------------------
__global__ __launch_bounds__(256) void prep_kernel(
    const float* __restrict__ x, const int* __restrict__ qw,
    const float* __restrict__ u, const float* __restrict__ vt,
    short* __restrict__ xb, short* __restrict__ wb) {
    const int b = blockIdx.x;
    const int t = threadIdx.x;

    if (b >= RW_BLOCKS) {
        const int n8 = (M_DIM * IN_F) / 8;
        int tid = (b - RW_BLOCKS) * 256 + t;
        for (int i = tid; i < n8; i += CV_BLOCKS * 256) {
            f32x4 a = ((const f32x4*)x)[2 * i];
            f32x4 c = ((const f32x4*)x)[2 * i + 1];
            short8 o;
            o[0] = f2bf(a[0]); o[1] = f2bf(a[1]); o[2] = f2bf(a[2]); o[3] = f2bf(a[3]);
            o[4] = f2bf(c[0]); o[5] = f2bf(c[1]); o[6] = f2bf(c[2]); o[7] = f2bf(c[3]);
            ((short8*)xb)[i] = o;
        }
        return;
    }

    __shared__ float vts[64][128];
    __shared__ float us[64][64];

    const int c0 = (b & 31) * 128;
    const int o0 = (b >> 5) * 64;

    {
        const f32x4* vt4 = (const f32x4*)vt;
        const int l32 = t & 31;
        const int r0w = t >> 5;
#pragma unroll
        for (int j = 0; j < 8; ++j) {
            int row = r0w + j * 8;
            ((f32x4*)&vts[row][0])[l32] = vt4[(size_t)row * 1024 + (c0 >> 2) + l32];
        }
    }
    {
        const int o = t & 63, q = t >> 6;
#pragma unroll
        for (int i = 0; i < 4; ++i) {
            f32x4 v = ((const f32x4*)u)[((size_t)i * OUT_F + o0 + o) * 4 + q];
            us[i * 16 + q * 4 + 0][o] = v[0];
            us[i * 16 + q * 4 + 1][o] = v[1];
            us[i * 16 + q * 4 + 2][o] = v[2];
            us[i * 16 + q * 4 + 3][o] = v[3];
        }
    }
    __syncthreads();

    const int to = (t >> 4) * 4;
    const int tc = (t & 15) * 8;

    float wacc[4][8];
#pragma unroll
    for (int r = 0; r < 4; ++r)
#pragma unroll
        for (int c = 0; c < 8; ++c) wacc[r][c] = 0.f;

#pragma unroll
    for (int i = 0; i < W_BIT; ++i) {
        float dot[4][8];
#pragma unroll
        for (int r = 0; r < 4; ++r)
#pragma unroll
            for (int c = 0; c < 8; ++c) dot[r][c] = 0.f;
#pragma unroll
        for (int k = 0; k < KRANK; ++k) {
            f32x4 uv = *(const f32x4*)&us[i * 16 + k][to];
            f32x4 v0 = *(const f32x4*)&vts[i * 16 + k][tc];
            f32x4 v1 = *(const f32x4*)&vts[i * 16 + k][tc + 4];
#pragma unroll
            for (int r = 0; r < 4; ++r) {
#pragma unroll
                for (int c = 0; c < 4; ++c) {
                    dot[r][c]     += uv[r] * v0[c];
                    dot[r][c + 4] += uv[r] * v1[c];
                }
            }
        }
#pragma unroll
        for (int r = 0; r < 4; ++r) {
            unsigned byte = (unsigned)qw[i * QW_PLANE + (((o0 + to + r) * IN_F + c0 + tc) >> 3)];
#pragma unroll
            for (int c = 0; c < 8; ++c)
                wacc[r][c] += ((byte >> c) & 1u) ? dot[r][c] : -dot[r][c];
        }
    }
#pragma unroll
    for (int r = 0; r < 4; ++r) {
        short8 o8;
#pragma unroll
        for (int c = 0; c < 8; ++c) o8[c] = f2bf(wacc[r][c]);
        *(short8*)&wb[(size_t)(o0 + to + r) * IN_F + c0 + tc] = o8;
    }
}

// ---------------------------------------------------------------------------
// GEMM: m201 8-phase port, RACE-FIXED: vmcnt gate at ph4-END followed by a
// barrier (vmcnt is per-wave; only VMC -> BAR -> read proves ALL waves'
// global_load_lds slices landed). Ledger: at tile T ph4-end, outstanding =
// [A(T+1) 4, B(T+1) 4, A(T+2) 4]; VMC(4) drains A(T+1)+B(T+1) = exactly what
// tile T+1 reads after the barrier. 256x256, BK=64, 8 waves (2x4), full-tile
// double buffers, 8-granule XOR swizzle, row-half staging (B(T+1)@ph1/2,
// A(T+2)@ph3/4), snake quadrant MFMA (ph4 reads nothing), 2 barriers/phase.
// ---------------------------------------------------------------------------
__global__ __launch_bounds__(512, 2) void gemm256_kernel(
    const short* __restrict__ A, const short* __restrict__ B, float* __restrict__ C) {
    extern __shared__ short lds[];

    const int t = threadIdx.x;
    const int lane = t & 63, wid = t >> 6;
    const int wr = wid >> 2, wc = wid & 3;       // 2 x 4 wave grid, wave 128x64
    const int fr = lane & 15, fq = lane >> 4;

    const int bid = blockIdx.x;
    const int cpx = gridDim.x >> 3;              // grid 1376 % 8 == 0
    const int swzb = (bid & 7) * cpx + (bid >> 3);
    const int bm = swzb / NBN, bn = swzb % NBN;
    const long row0 = (long)bm * 256, col0 = (long)bn * 256;

    // ---- fragment read bases: 8-granule perm, two kk base addresses
    const int f7 = fr & 7;
    const int g0 = fq ^ f7;              // kk=0 physical granule
    const int g1 = (4 + fq) ^ f7;        // kk=1 physical granule
    const int arow = (wr * 128 + fr) * 64;
    const int brow = (wc * 64 + fr) * 64;
    const unsigned av0 = (unsigned)(size_t)((__attribute__((address_space(3))) short*)lds + arow + g0 * 8);
    const unsigned av1 = (unsigned)(size_t)((__attribute__((address_space(3))) short*)lds + arow + g1 * 8);
    const unsigned bv0 = (unsigned)(size_t)((__attribute__((address_space(3))) short*)lds + 32768 + brow + g0 * 8);
    const unsigned bv1 = (unsigned)(size_t)((__attribute__((address_space(3))) short*)lds + 32768 + brow + g1 * 8);

    // ---- staging: linear LDS dest, inverse-swizzled global source
    const int sswz = (((t & 7) ^ ((t >> 3) & 7)) << 3);      // shorts
    const short* pA = A + (row0 + (t >> 3)) * (size_t)K_DIM + sswz;
    const short* pB = B + (col0 + (t >> 3)) * (size_t)K_DIM + sswz;

    f32x4 acc[8][4];
#pragma unroll
    for (int m = 0; m < 8; ++m)
#pragma unroll
        for (int n = 0; n < 4; ++n) acc[m][n] = (f32x4)0.f;

    short8 a0[8], a1[8], b0[4], b1[4];   // a: [kk*4+m], b: [kk*2+n]

#define STGA(P, H, OFFB) do {                                               \
    async16(&lds[(P) * 16384 + (2 * (H)) * 4096 + t * 8],                   \
            (const char*)(pA + (size_t)(2 * (H)) * 64 * K_DIM) + (OFFB));   \
    async16(&lds[(P) * 16384 + (2 * (H) + 1) * 4096 + t * 8],               \
            (const char*)(pA + (size_t)(2 * (H) + 1) * 64 * K_DIM) + (OFFB)); \
} while (0)
#define STGB(P, H, OFFB) do {                                               \
    async16(&lds[32768 + (P) * 16384 + (2 * (H)) * 4096 + t * 8],           \
            (const char*)(pB + (size_t)(2 * (H)) * 64 * K_DIM) + (OFFB));   \
    async16(&lds[32768 + (P) * 16384 + (2 * (H) + 1) * 4096 + t * 8],       \
            (const char*)(pB + (size_t)(2 * (H) + 1) * 64 * K_DIM) + (OFFB)); \
} while (0)

#define RDA(SET, P, MH) do {                                                \
    DSR(SET[0], av0, ((P) * 16384 + (MH) * 4096 + 0 * 1024) * 2);           \
    DSR(SET[1], av0, ((P) * 16384 + (MH) * 4096 + 1 * 1024) * 2);           \
    DSR(SET[2], av0, ((P) * 16384 + (MH) * 4096 + 2 * 1024) * 2);           \
    DSR(SET[3], av0, ((P) * 16384 + (MH) * 4096 + 3 * 1024) * 2);           \
    DSR(SET[4], av1, ((P) * 16384 + (MH) * 4096 + 0 * 1024) * 2);           \
    DSR(SET[5], av1, ((P) * 16384 + (MH) * 4096 + 1 * 1024) * 2);           \
    DSR(SET[6], av1, ((P) * 16384 + (MH) * 4096 + 2 * 1024) * 2);           \
    DSR(SET[7], av1, ((P) * 16384 + (MH) * 4096 + 3 * 1024) * 2);           \
} while (0)

#define RDB(SET, P, NH) do {                                                \
    DSR(SET[0], bv0, ((P) * 16384 + (NH) * 2048 + 0 * 1024) * 2);           \
    DSR(SET[1], bv0, ((P) * 16384 + (NH) * 2048 + 1 * 1024) * 2);           \
    DSR(SET[2], bv1, ((P) * 16384 + (NH) * 2048 + 0 * 1024) * 2);           \
    DSR(SET[3], bv1, ((P) * 16384 + (NH) * 2048 + 1 * 1024) * 2);           \
} while (0)

#define MMAQ(ASET, BSET, MH, NH) do { PRIO1();                              \
    _Pragma("unroll") for (int m = 0; m < 4; ++m)                           \
        _Pragma("unroll") for (int n = 0; n < 2; ++n) {                     \
            acc[(MH) * 4 + m][(NH) * 2 + n] =                               \
                __builtin_amdgcn_mfma_f32_16x16x32_bf16(                    \
                    ASET[m], BSET[n], acc[(MH) * 4 + m][(NH) * 2 + n], 0, 0, 0); \
            acc[(MH) * 4 + m][(NH) * 2 + n] =                               \
                __builtin_amdgcn_mfma_f32_16x16x32_bf16(                    \
                    ASET[4 + m], BSET[2 + n], acc[(MH) * 4 + m][(NH) * 2 + n], 0, 0, 0); \
        }                                                                   \
    PRIO0(); __builtin_amdgcn_sched_barrier(0); } while (0)

// one K-tile (4 phases). Gate at ph4-END: VMC(4) then BAR -> next tile's
// reads are provably landed across ALL waves.
#define TILE(P, OFFB, OFFA) do {                                            \
    /* ph1: (A0,B0) */                                                      \
    RDA(a0, P, 0); RDB(b0, P, 0);                                           \
    STGB(1 - (P), 0, OFFB);                                                 \
    BAR(); LGKM0(); MMAQ(a0, b0, 0, 0); BAR();                              \
    /* ph2: (A1,B0) */                                                      \
    RDA(a1, P, 1);                                                          \
    STGB(1 - (P), 1, OFFB);                                                 \
    BAR(); LGKM0(); MMAQ(a1, b0, 1, 0); BAR();                              \
    /* ph3: (A1,B1) */                                                      \
    RDB(b1, P, 1);                                                          \
    STGA(P, 0, OFFA);                                                       \
    BAR(); LGKM0(); MMAQ(a1, b1, 1, 1); BAR();                              \
    /* ph4: (A0,B1), no reads; gate then barrier */                         \
    STGA(P, 1, OFFA);                                                       \
    BAR(); MMAQ(a0, b1, 0, 1); VMC(4); BAR();                               \
} while (0)

    // ---- prologue: tile0 all 4 units + tile1 A units = 12 gll
    STGA(0, 0, 0); STGA(0, 1, 0);
    STGB(0, 0, 0); STGB(0, 1, 0);
    STGA(1, 0, 128); STGA(1, 1, 128);
    VMC(4);          // drain A(0)+B(0) (8 oldest); A(1) stays in flight
    BAR();           // all waves' tile0 slices proven landed

    // ---- main loop: 31 iters x 2 tiles (T0..T61)
    for (int it = 0; it < 31; ++it) {
        TILE(0, 128, 256);   // even tile: B(T+1)@+128B, A(T+2)@+256B
        TILE(1, 256, 384);   // odd tile:  B(T+2)@+256B, A(T+3)@+384B
        pA += 128; pB += 128;   // +256 B = 2 K-tiles
    }

    // ---- tail T62 (buf0): stages only B(63); ph4-end gate VMC(0)
    RDA(a0, 0, 0); RDB(b0, 0, 0);
    STGB(1, 0, 128);
    BAR(); LGKM0(); MMAQ(a0, b0, 0, 0); BAR();
    RDA(a1, 0, 1);
    STGB(1, 1, 128);
    BAR(); LGKM0(); MMAQ(a1, b0, 1, 0); BAR();
    RDB(b1, 0, 1);
    BAR(); LGKM0(); MMAQ(a1, b1, 1, 1); BAR();
    BAR(); MMAQ(a0, b1, 0, 1); VMC(0); BAR();
    // ---- tail T63 (buf1): no stages, no gates
    RDA(a0, 1, 0); RDB(b0, 1, 0);
    BAR(); LGKM0(); MMAQ(a0, b0, 0, 0); BAR();
    RDA(a1, 1, 1);
    BAR(); LGKM0(); MMAQ(a1, b0, 1, 0); BAR();
    RDB(b1, 1, 1);
    BAR(); LGKM0(); MMAQ(a1, b1, 1, 1); BAR();
    BAR(); MMAQ(a0, b1, 0, 1);

    // ---- epilogue: C/D layout col = lane&15, row = (lane>>4)*4 + j
#pragma unroll
    for (int m = 0; m < 8; ++m) {
#pragma unroll
        for (int n = 0; n < 4; ++n) {
            f32x4 v = acc[m][n];
            long r0 = row0 + wr * 128 + m * 16 + fq * 4;
            long cc = col0 + wc * 64 + n * 16 + fr;
#pragma unroll
            for (int jj = 0; jj < 4; ++jj)
                C[(size_t)(r0 + jj) * N_DIM + cc] = v[jj];
        }
    }
#undef STGA
#undef STGB
#undef RDA
#undef RDB
#undef MMAQ
#undef TILE
}

// ---------------------------------------------------------------------------
extern "C" void kernel_launch(void* const* d_in, const int* in_sizes, int n_in,
                              void* d_out, int out_size, void* d_ws, size_t ws_size,
                              hipStream_t stream) {
    const float* x  = (const float*)d_in[0];
    const int*   qw = (const int*)d_in[1];
    const float* u  = (const float*)d_in[2];
    const float* vt = (const float*)d_in[3];
    float* out = (float*)d_out;

    const size_t wb_bytes = (size_t)OUT_F * IN_F * 2;
    short* wb = (short*)d_ws;
    short* xb = (short*)((char*)d_ws + wb_bytes);

    (void)hipFuncSetAttribute((const void*)gemm256_kernel,
                              hipFuncAttributeMaxDynamicSharedMemorySize, 131072);

    hipLaunchKernelGGL(prep_kernel, dim3(RW_BLOCKS + CV_BLOCKS), dim3(256), 0, stream,
                       x, qw, u, vt, xb, wb);
    hipLaunchKernelGGL(gemm256_kernel, dim3((M_DIM / 256) * (N_DIM / 256)), dim3(512), 131072,
                       stream, xb, wb, out);
}

// Round 14
// 787.181 us; speedup vs baseline: 1.4222x; 1.0445x over previous
//
#include <hip/hip_runtime.h>
#include <hip/hip_bf16.h>

#define W_BIT 4
#define OUT_F 11008
#define IN_F 4096
#define KRANK 16
#define M_DIM 8192
#define QW_PLANE (OUT_F * IN_F / 8)

#define N_DIM OUT_F
#define K_DIM 4096
#define NBN 43             // N_DIM / 256
#define RW_BLOCKS 5504
#define CV_BLOCKS 1024

typedef __attribute__((ext_vector_type(8))) short short8;
typedef __attribute__((ext_vector_type(4))) float f32x4;

__device__ __forceinline__ short f2bf(float f) {
    union { float f; unsigned u; } v;
    v.f = f;
    unsigned r = v.u + 0x7fffu + ((v.u >> 16) & 1u);
    return (short)(r >> 16);
}

__device__ __forceinline__ void async16(void* lds_p, const void* g) {
    __builtin_amdgcn_global_load_lds(
        (const __attribute__((address_space(1))) unsigned int*)g,
        (__attribute__((address_space(3))) unsigned int*)lds_p,
        16, 0, 0);
}

#define BAR() __builtin_amdgcn_s_barrier()
#define LGKM0() do { asm volatile("s_waitcnt lgkmcnt(0)" ::: "memory"); \
                     __builtin_amdgcn_sched_barrier(0); } while (0)
#define VMC(n) do { asm volatile("s_waitcnt vmcnt(" #n ")" ::: "memory"); \
                    __builtin_amdgcn_sched_barrier(0); } while (0)
#define PRIO1() __builtin_amdgcn_s_setprio(1)
#define PRIO0() __builtin_amdgcn_s_setprio(0)

// volatile asm ds_read_b128: issue order pinned; byte-imm offset
#define DSR(DST, AV, IMM) \
    asm volatile("ds_read_b128 %0, %1 offset:%2" : "=v"(DST) : "v"(AV), "n"(IMM))

// volatile asm MFMA: issue order pinned -> source-level interleave with DSR
// is the emitted interleave (builtins would be scheduler-movable).
#define MFA(D, S0, S1) \
    asm volatile("v_mfma_f32_16x16x32_bf16 %0, %1, %2, %0" \
                 : "+a"(D) : "v"(S0), "v"(S1))

// ---------------------------------------------------------------------------
// Fused prep (unchanged, passing): reconstruct w + convert x.
// ---------------------------------------------------------------------------
__global__ __launch_bounds__(256) void prep_kernel(
    const float* __restrict__ x, const int* __restrict__ qw,
    const float* __restrict__ u, const float* __restrict__ vt,
    short* __restrict__ xb, short* __restrict__ wb) {
    const int b = blockIdx.x;
    const int t = threadIdx.x;

    if (b >= RW_BLOCKS) {
        const int n8 = (M_DIM * IN_F) / 8;
        int tid = (b - RW_BLOCKS) * 256 + t;
        for (int i = tid; i < n8; i += CV_BLOCKS * 256) {
            f32x4 a = ((const f32x4*)x)[2 * i];
            f32x4 c = ((const f32x4*)x)[2 * i + 1];
            short8 o;
            o[0] = f2bf(a[0]); o[1] = f2bf(a[1]); o[2] = f2bf(a[2]); o[3] = f2bf(a[3]);
            o[4] = f2bf(c[0]); o[5] = f2bf(c[1]); o[6] = f2bf(c[2]); o[7] = f2bf(c[3]);
            ((short8*)xb)[i] = o;
        }
        return;
    }

    __shared__ float vts[64][128];
    __shared__ float us[64][64];

    const int c0 = (b & 31) * 128;
    const int o0 = (b >> 5) * 64;

    {
        const f32x4* vt4 = (const f32x4*)vt;
        const int l32 = t & 31;
        const int r0w = t >> 5;
#pragma unroll
        for (int j = 0; j < 8; ++j) {
            int row = r0w + j * 8;
            ((f32x4*)&vts[row][0])[l32] = vt4[(size_t)row * 1024 + (c0 >> 2) + l32];
        }
    }
    {
        const int o = t & 63, q = t >> 6;
#pragma unroll
        for (int i = 0; i < 4; ++i) {
            f32x4 v = ((const f32x4*)u)[((size_t)i * OUT_F + o0 + o) * 4 + q];
            us[i * 16 + q * 4 + 0][o] = v[0];
            us[i * 16 + q * 4 + 1][o] = v[1];
            us[i * 16 + q * 4 + 2][o] = v[2];
            us[i * 16 + q * 4 + 3][o] = v[3];
        }
    }
    __syncthreads();

    const int to = (t >> 4) * 4;
    const int tc = (t & 15) * 8;

    float wacc[4][8];
#pragma unroll
    for (int r = 0; r < 4; ++r)
#pragma unroll
        for (int c = 0; c < 8; ++c) wacc[r][c] = 0.f;

#pragma unroll
    for (int i = 0; i < W_BIT; ++i) {
        float dot[4][8];
#pragma unroll
        for (int r = 0; r < 4; ++r)
#pragma unroll
            for (int c = 0; c < 8; ++c) dot[r][c] = 0.f;
#pragma unroll
        for (int k = 0; k < KRANK; ++k) {
            f32x4 uv = *(const f32x4*)&us[i * 16 + k][to];
            f32x4 v0 = *(const f32x4*)&vts[i * 16 + k][tc];
            f32x4 v1 = *(const f32x4*)&vts[i * 16 + k][tc + 4];
#pragma unroll
            for (int r = 0; r < 4; ++r) {
#pragma unroll
                for (int c = 0; c < 4; ++c) {
                    dot[r][c]     += uv[r] * v0[c];
                    dot[r][c + 4] += uv[r] * v1[c];
                }
            }
        }
#pragma unroll
        for (int r = 0; r < 4; ++r) {
            unsigned byte = (unsigned)qw[i * QW_PLANE + (((o0 + to + r) * IN_F + c0 + tc) >> 3)];
#pragma unroll
            for (int c = 0; c < 8; ++c)
                wacc[r][c] += ((byte >> c) & 1u) ? dot[r][c] : -dot[r][c];
        }
    }
#pragma unroll
    for (int r = 0; r < 4; ++r) {
        short8 o8;
#pragma unroll
        for (int c = 0; c < 8; ++c) o8[c] = f2bf(wacc[r][c]);
        *(short8*)&wb[(size_t)(o0 + to + r) * IN_F + c0 + tc] = o8;
    }
}

// ---------------------------------------------------------------------------
// GEMM: R13 geometry (256x256, BK=64, 8 waves 2x4, full-tile double buffers,
// 8-granule XOR swizzle, row-half staging) with INTRA-PHASE INTERLEAVE:
// every instruction in the K-loop is volatile asm (MFMA + ds_read), so
// next-phase ds_reads are issued BETWEEN MFMA quads -> LDS pipe serviced
// under the MFMA-issue window instead of after it. 1 barrier/phase. Gate
// moved to ph3-end (VMC(2)+BAR: drains A(T+1)+B(T+1), leaves A(T+2)H0 in
// flight); ph4 pre-reads next tile's a0/b0 interleaved (a0 self-overwrite
// ordered >=1 MFMA-quad after last consumer).
// ---------------------------------------------------------------------------
__global__ __launch_bounds__(512, 2) void gemm256_kernel(
    const short* __restrict__ A, const short* __restrict__ B, float* __restrict__ C) {
    extern __shared__ short lds[];

    const int t = threadIdx.x;
    const int lane = t & 63, wid = t >> 6;
    const int wr = wid >> 2, wc = wid & 3;       // 2 x 4 wave grid, wave 128x64
    const int fr = lane & 15, fq = lane >> 4;

    const int bid = blockIdx.x;
    const int cpx = gridDim.x >> 3;              // grid 1376 % 8 == 0
    const int swzb = (bid & 7) * cpx + (bid >> 3);
    const int bm = swzb / NBN, bn = swzb % NBN;
    const long row0 = (long)bm * 256, col0 = (long)bn * 256;

    // ---- fragment read bases: 8-granule perm, two kk base addresses
    const int f7 = fr & 7;
    const int g0 = fq ^ f7;
    const int g1 = (4 + fq) ^ f7;
    const int arow = (wr * 128 + fr) * 64;
    const int brow = (wc * 64 + fr) * 64;
    const unsigned av0 = (unsigned)(size_t)((__attribute__((address_space(3))) short*)lds + arow + g0 * 8);
    const unsigned av1 = (unsigned)(size_t)((__attribute__((address_space(3))) short*)lds + arow + g1 * 8);
    const unsigned bv0 = (unsigned)(size_t)((__attribute__((address_space(3))) short*)lds + 32768 + brow + g0 * 8);
    const unsigned bv1 = (unsigned)(size_t)((__attribute__((address_space(3))) short*)lds + 32768 + brow + g1 * 8);

    // ---- staging: linear LDS dest, inverse-swizzled global source
    const int sswz = (((t & 7) ^ ((t >> 3) & 7)) << 3);
    const short* pA = A + (row0 + (t >> 3)) * (size_t)K_DIM + sswz;
    const short* pB = B + (col0 + (t >> 3)) * (size_t)K_DIM + sswz;

    f32x4 acc[8][4];
#pragma unroll
    for (int m = 0; m < 8; ++m)
#pragma unroll
        for (int n = 0; n < 4; ++n) acc[m][n] = (f32x4)0.f;

    short8 a0[8], a1[8], b0[4], b1[4];   // a: [kk*4+m], b: [kk*2+n]

// byte-offset immediates into swizzled slots
#define AOFF(P, MH, M) (((P) * 16384 + (MH) * 4096 + (M) * 1024) * 2)
#define BOFF(P, NH, N) (((P) * 16384 + (NH) * 2048 + (N) * 1024) * 2)

#define STGA(P, H, OFFB) do {                                               \
    async16(&lds[(P) * 16384 + (2 * (H)) * 4096 + t * 8],                   \
            (const char*)(pA + (size_t)(2 * (H)) * 64 * K_DIM) + (OFFB));   \
    async16(&lds[(P) * 16384 + (2 * (H) + 1) * 4096 + t * 8],               \
            (const char*)(pA + (size_t)(2 * (H) + 1) * 64 * K_DIM) + (OFFB)); \
} while (0)
#define STGB(P, H, OFFB) do {                                               \
    async16(&lds[32768 + (P) * 16384 + (2 * (H)) * 4096 + t * 8],           \
            (const char*)(pB + (size_t)(2 * (H)) * 64 * K_DIM) + (OFFB));   \
    async16(&lds[32768 + (P) * 16384 + (2 * (H) + 1) * 4096 + t * 8],       \
            (const char*)(pB + (size_t)(2 * (H) + 1) * 64 * K_DIM) + (OFFB)); \
} while (0)

// 4 MFMA for one m-row of a quadrant: n0kk0, n1kk0, n0kk1, n1kk1
#define MF4(ASET, BSET, MH, NH, M) do {                                     \
    MFA(acc[(MH) * 4 + (M)][(NH) * 2 + 0], ASET[M], BSET[0]);               \
    MFA(acc[(MH) * 4 + (M)][(NH) * 2 + 1], ASET[M], BSET[1]);               \
    MFA(acc[(MH) * 4 + (M)][(NH) * 2 + 0], ASET[4 + (M)], BSET[2]);         \
    MFA(acc[(MH) * 4 + (M)][(NH) * 2 + 1], ASET[4 + (M)], BSET[3]);         \
} while (0)

// ---- one K-tile, 4 phases, 1 barrier each. P literal.
#define TILE(P, OFFB, OFFA, GATE_N, LAST)  do {                             \
    /* ph1: Q00 (a0,b0); interleave DSR a1 (ph2 operands) */                \
    LGKM0();                                                                \
    STGB(1 - (P), 0, OFFB);                                                 \
    PRIO1();                                                                \
    MF4(a0, b0, 0, 0, 0);                                                   \
    DSR(a1[0], av0, AOFF(P, 1, 0)); DSR(a1[4], av1, AOFF(P, 1, 0));         \
    MF4(a0, b0, 0, 0, 1);                                                   \
    DSR(a1[1], av0, AOFF(P, 1, 1)); DSR(a1[5], av1, AOFF(P, 1, 1));         \
    MF4(a0, b0, 0, 0, 2);                                                   \
    DSR(a1[2], av0, AOFF(P, 1, 2)); DSR(a1[6], av1, AOFF(P, 1, 2));         \
    MF4(a0, b0, 0, 0, 3);                                                   \
    DSR(a1[3], av0, AOFF(P, 1, 3)); DSR(a1[7], av1, AOFF(P, 1, 3));         \
    PRIO0(); BAR();                                                         \
    /* ph2: Q10 (a1,b0); interleave DSR b1 (ph3 operands) */                \
    LGKM0();                                                                \
    STGB(1 - (P), 1, OFFB);                                                 \
    PRIO1();                                                                \
    MF4(a1, b0, 1, 0, 0);                                                   \
    DSR(b1[0], bv0, BOFF(P, 1, 0)); DSR(b1[2], bv1, BOFF(P, 1, 0));         \
    MF4(a1, b0, 1, 0, 1);                                                   \
    DSR(b1[1], bv0, BOFF(P, 1, 1)); DSR(b1[3], bv1, BOFF(P, 1, 1));         \
    MF4(a1, b0, 1, 0, 2);                                                   \
    MF4(a1, b0, 1, 0, 3);                                                   \
    PRIO0(); BAR();                                                         \
    /* ph3: Q11 (a1,b1); gate at end (VMC->BAR proves next tile landed) */  \
    LGKM0();                                                                \
    STGA(P, 0, OFFA);                                                       \
    PRIO1();                                                                \
    MF4(a1, b1, 1, 1, 0); MF4(a1, b1, 1, 1, 1);                             \
    MF4(a1, b1, 1, 1, 2); MF4(a1, b1, 1, 1, 3);                             \
    PRIO0(); VMC(GATE_N); BAR();                                            \
    /* ph4: Q01 (a0,b1); interleave next-tile a0'/b0' (parity 1-P) */       \
    STGA(P, 1, OFFA);                                                       \
    PRIO1();                                                                \
    MF4(a0, b1, 0, 1, 0);                                                   \
    MF4(a0, b1, 0, 1, 1);                                                   \
    if (!(LAST)) { DSR(a0[0], av0, AOFF(1 - (P), 0, 0));                    \
                   DSR(a0[4], av1, AOFF(1 - (P), 0, 0)); }                  \
    MF4(a0, b1, 0, 1, 2);                                                   \
    if (!(LAST)) { DSR(a0[1], av0, AOFF(1 - (P), 0, 1));                    \
                   DSR(a0[5], av1, AOFF(1 - (P), 0, 1)); }                  \
    MF4(a0, b1, 0, 1, 3);                                                   \
    if (!(LAST)) {                                                          \
        DSR(a0[2], av0, AOFF(1 - (P), 0, 2)); DSR(a0[6], av1, AOFF(1 - (P), 0, 2)); \
        DSR(a0[3], av0, AOFF(1 - (P), 0, 3)); DSR(a0[7], av1, AOFF(1 - (P), 0, 3)); \
        DSR(b0[0], bv0, BOFF(1 - (P), 0, 0)); DSR(b0[2], bv1, BOFF(1 - (P), 0, 0)); \
        DSR(b0[1], bv0, BOFF(1 - (P), 0, 1)); DSR(b0[3], bv1, BOFF(1 - (P), 0, 1)); \
    }                                                                       \
    PRIO0(); BAR();                                                         \
} while (0)

    // ---- prologue: A(0),B(0),A(1) = 12 gll; gate; pre-read tile0 a0/b0
    STGA(0, 0, 0); STGA(0, 1, 0);
    STGB(0, 0, 0); STGB(0, 1, 0);
    STGA(1, 0, 128); STGA(1, 1, 128);
    VMC(4);          // A(0)+B(0) landed; A(1) in flight
    BAR();
    DSR(a0[0], av0, AOFF(0, 0, 0)); DSR(a0[4], av1, AOFF(0, 0, 0));
    DSR(a0[1], av0, AOFF(0, 0, 1)); DSR(a0[5], av1, AOFF(0, 0, 1));
    DSR(a0[2], av0, AOFF(0, 0, 2)); DSR(a0[6], av1, AOFF(0, 0, 2));
    DSR(a0[3], av0, AOFF(0, 0, 3)); DSR(a0[7], av1, AOFF(0, 0, 3));
    DSR(b0[0], bv0, BOFF(0, 0, 0)); DSR(b0[2], bv1, BOFF(0, 0, 0));
    DSR(b0[1], bv0, BOFF(0, 0, 1)); DSR(b0[3], bv1, BOFF(0, 0, 1));

    // ---- main loop: 31 iters x 2 tiles (T0..T61)
    for (int it = 0; it < 31; ++it) {
        TILE(0, 128, 256, 2, 0);   // even: B(T+1)@+128B, A(T+2)@+256B
        TILE(1, 256, 384, 2, 0);   // odd:  B(T+2)@+256B, A(T+3)@+384B
        pA += 128; pB += 128;      // +256 B = 2 K-tiles
    }

    // ---- tail T62 (P=0): stages only B(63); gate VMC(0); ph4 pre-reads T63
    LGKM0(); STGB(1, 0, 128);
    PRIO1();
    MF4(a0, b0, 0, 0, 0);
    DSR(a1[0], av0, AOFF(0, 1, 0)); DSR(a1[4], av1, AOFF(0, 1, 0));
    MF4(a0, b0, 0, 0, 1);
    DSR(a1[1], av0, AOFF(0, 1, 1)); DSR(a1[5], av1, AOFF(0, 1, 1));
    MF4(a0, b0, 0, 0, 2);
    DSR(a1[2], av0, AOFF(0, 1, 2)); DSR(a1[6], av1, AOFF(0, 1, 2));
    MF4(a0, b0, 0, 0, 3);
    DSR(a1[3], av0, AOFF(0, 1, 3)); DSR(a1[7], av1, AOFF(0, 1, 3));
    PRIO0(); BAR();
    LGKM0(); STGB(1, 1, 128);
    PRIO1();
    MF4(a1, b0, 1, 0, 0);
    DSR(b1[0], bv0, BOFF(0, 1, 0)); DSR(b1[2], bv1, BOFF(0, 1, 0));
    MF4(a1, b0, 1, 0, 1);
    DSR(b1[1], bv0, BOFF(0, 1, 1)); DSR(b1[3], bv1, BOFF(0, 1, 1));
    MF4(a1, b0, 1, 0, 2); MF4(a1, b0, 1, 0, 3);
    PRIO0(); BAR();
    LGKM0();
    PRIO1();
    MF4(a1, b1, 1, 1, 0); MF4(a1, b1, 1, 1, 1);
    MF4(a1, b1, 1, 1, 2); MF4(a1, b1, 1, 1, 3);
    PRIO0(); VMC(0); BAR();
    PRIO1();
    MF4(a0, b1, 0, 1, 0); MF4(a0, b1, 0, 1, 1);
    DSR(a0[0], av0, AOFF(1, 0, 0)); DSR(a0[4], av1, AOFF(1, 0, 0));
    MF4(a0, b1, 0, 1, 2);
    DSR(a0[1], av0, AOFF(1, 0, 1)); DSR(a0[5], av1, AOFF(1, 0, 1));
    MF4(a0, b1, 0, 1, 3);
    DSR(a0[2], av0, AOFF(1, 0, 2)); DSR(a0[6], av1, AOFF(1, 0, 2));
    DSR(a0[3], av0, AOFF(1, 0, 3)); DSR(a0[7], av1, AOFF(1, 0, 3));
    DSR(b0[0], bv0, BOFF(1, 0, 0)); DSR(b0[2], bv1, BOFF(1, 0, 0));
    DSR(b0[1], bv0, BOFF(1, 0, 1)); DSR(b0[3], bv1, BOFF(1, 0, 1));
    PRIO0(); BAR();
    // ---- tail T63 (P=1): no stages, no gates, no pre-reads
    LGKM0();
    PRIO1();
    MF4(a0, b0, 0, 0, 0);
    DSR(a1[0], av0, AOFF(1, 1, 0)); DSR(a1[4], av1, AOFF(1, 1, 0));
    MF4(a0, b0, 0, 0, 1);
    DSR(a1[1], av0, AOFF(1, 1, 1)); DSR(a1[5], av1, AOFF(1, 1, 1));
    MF4(a0, b0, 0, 0, 2);
    DSR(a1[2], av0, AOFF(1, 1, 2)); DSR(a1[6], av1, AOFF(1, 1, 2));
    MF4(a0, b0, 0, 0, 3);
    DSR(a1[3], av0, AOFF(1, 1, 3)); DSR(a1[7], av1, AOFF(1, 1, 3));
    PRIO0(); BAR();
    LGKM0();
    PRIO1();
    MF4(a1, b0, 1, 0, 0);
    DSR(b1[0], bv0, BOFF(1, 1, 0)); DSR(b1[2], bv1, BOFF(1, 1, 0));
    MF4(a1, b0, 1, 0, 1);
    DSR(b1[1], bv0, BOFF(1, 1, 1)); DSR(b1[3], bv1, BOFF(1, 1, 1));
    MF4(a1, b0, 1, 0, 2); MF4(a1, b0, 1, 0, 3);
    PRIO0(); BAR();
    LGKM0();
    PRIO1();
    MF4(a1, b1, 1, 1, 0); MF4(a1, b1, 1, 1, 1);
    MF4(a1, b1, 1, 1, 2); MF4(a1, b1, 1, 1, 3);
    MF4(a0, b1, 0, 1, 0); MF4(a0, b1, 0, 1, 1);
    MF4(a0, b1, 0, 1, 2); MF4(a0, b1, 0, 1, 3);
    PRIO0();

    // ---- epilogue: C/D layout col = lane&15, row = (lane>>4)*4 + j
#pragma unroll
    for (int m = 0; m < 8; ++m) {
#pragma unroll
        for (int n = 0; n < 4; ++n) {
            f32x4 v = acc[m][n];
            long r0 = row0 + wr * 128 + m * 16 + fq * 4;
            long cc = col0 + wc * 64 + n * 16 + fr;
#pragma unroll
            for (int jj = 0; jj < 4; ++jj)
                C[(size_t)(r0 + jj) * N_DIM + cc] = v[jj];
        }
    }
#undef STGA
#undef STGB
#undef MF4
#undef TILE
#undef AOFF
#undef BOFF
}

// ---------------------------------------------------------------------------
extern "C" void kernel_launch(void* const* d_in, const int* in_sizes, int n_in,
                              void* d_out, int out_size, void* d_ws, size_t ws_size,
                              hipStream_t stream) {
    const float* x  = (const float*)d_in[0];
    const int*   qw = (const int*)d_in[1];
    const float* u  = (const float*)d_in[2];
    const float* vt = (const float*)d_in[3];
    float* out = (float*)d_out;

    const size_t wb_bytes = (size_t)OUT_F * IN_F * 2;
    short* wb = (short*)d_ws;
    short* xb = (short*)((char*)d_ws + wb_bytes);

    (void)hipFuncSetAttribute((const void*)gemm256_kernel,
                              hipFuncAttributeMaxDynamicSharedMemorySize, 131072);

    hipLaunchKernelGGL(prep_kernel, dim3(RW_BLOCKS + CV_BLOCKS), dim3(256), 0, stream,
                       x, qw, u, vt, xb, wb);
    hipLaunchKernelGGL(gemm256_kernel, dim3((M_DIM / 256) * (N_DIM / 256)), dim3(512), 131072,
                       stream, xb, wb, out);
}

// Round 15
// 772.627 us; speedup vs baseline: 1.4490x; 1.0188x over previous
//
#include <hip/hip_runtime.h>
#include <hip/hip_bf16.h>

#define W_BIT 4
#define OUT_F 11008
#define IN_F 4096
#define KRANK 16
#define M_DIM 8192
#define QW_PLANE (OUT_F * IN_F / 8)

#define N_DIM OUT_F
#define K_DIM 4096
#define NBN 43             // N_DIM / 256
#define RW_BLOCKS 5504
#define CV_BLOCKS 1024

typedef __attribute__((ext_vector_type(8))) short short8;
typedef __attribute__((ext_vector_type(4))) float f32x4;

__device__ __forceinline__ short f2bf(float f) {
    union { float f; unsigned u; } v;
    v.f = f;
    unsigned r = v.u + 0x7fffu + ((v.u >> 16) & 1u);
    return (short)(r >> 16);
}

__device__ __forceinline__ void async16(void* lds_p, const void* g) {
    __builtin_amdgcn_global_load_lds(
        (const __attribute__((address_space(1))) unsigned int*)g,
        (__attribute__((address_space(3))) unsigned int*)lds_p,
        16, 0, 0);
}

#define BAR() __builtin_amdgcn_s_barrier()
#define LGKM0() do { asm volatile("s_waitcnt lgkmcnt(0)" ::: "memory"); \
                     __builtin_amdgcn_sched_barrier(0); } while (0)
#define VMC(n) do { asm volatile("s_waitcnt vmcnt(" #n ")" ::: "memory"); \
                    __builtin_amdgcn_sched_barrier(0); } while (0)
#define PRIO1() __builtin_amdgcn_s_setprio(1)
#define PRIO0() __builtin_amdgcn_s_setprio(0)

// volatile asm ds_read_b128: issue order pinned; byte-imm offset
#define DSR(DST, AV, IMM) \
    asm volatile("ds_read_b128 %0, %1 offset:%2" : "=v"(DST) : "v"(AV), "n"(IMM))

// volatile asm MFMA: issue order pinned
#define MFA(D, S0, S1) \
    asm volatile("v_mfma_f32_16x16x32_bf16 %0, %1, %2, %0" \
                 : "+a"(D) : "v"(S0), "v"(S1))

// ---------------------------------------------------------------------------
// Fused prep (unchanged, passing): reconstruct w + convert x.
// ---------------------------------------------------------------------------
__global__ __launch_bounds__(256) void prep_kernel(
    const float* __restrict__ x, const int* __restrict__ qw,
    const float* __restrict__ u, const float* __restrict__ vt,
    short* __restrict__ xb, short* __restrict__ wb) {
    const int b = blockIdx.x;
    const int t = threadIdx.x;

    if (b >= RW_BLOCKS) {
        const int n8 = (M_DIM * IN_F) / 8;
        int tid = (b - RW_BLOCKS) * 256 + t;
        for (int i = tid; i < n8; i += CV_BLOCKS * 256) {
            f32x4 a = ((const f32x4*)x)[2 * i];
            f32x4 c = ((const f32x4*)x)[2 * i + 1];
            short8 o;
            o[0] = f2bf(a[0]); o[1] = f2bf(a[1]); o[2] = f2bf(a[2]); o[3] = f2bf(a[3]);
            o[4] = f2bf(c[0]); o[5] = f2bf(c[1]); o[6] = f2bf(c[2]); o[7] = f2bf(c[3]);
            ((short8*)xb)[i] = o;
        }
        return;
    }

    __shared__ float vts[64][128];
    __shared__ float us[64][64];

    const int c0 = (b & 31) * 128;
    const int o0 = (b >> 5) * 64;

    {
        const f32x4* vt4 = (const f32x4*)vt;
        const int l32 = t & 31;
        const int r0w = t >> 5;
#pragma unroll
        for (int j = 0; j < 8; ++j) {
            int row = r0w + j * 8;
            ((f32x4*)&vts[row][0])[l32] = vt4[(size_t)row * 1024 + (c0 >> 2) + l32];
        }
    }
    {
        const int o = t & 63, q = t >> 6;
#pragma unroll
        for (int i = 0; i < 4; ++i) {
            f32x4 v = ((const f32x4*)u)[((size_t)i * OUT_F + o0 + o) * 4 + q];
            us[i * 16 + q * 4 + 0][o] = v[0];
            us[i * 16 + q * 4 + 1][o] = v[1];
            us[i * 16 + q * 4 + 2][o] = v[2];
            us[i * 16 + q * 4 + 3][o] = v[3];
        }
    }
    __syncthreads();

    const int to = (t >> 4) * 4;
    const int tc = (t & 15) * 8;

    float wacc[4][8];
#pragma unroll
    for (int r = 0; r < 4; ++r)
#pragma unroll
        for (int c = 0; c < 8; ++c) wacc[r][c] = 0.f;

#pragma unroll
    for (int i = 0; i < W_BIT; ++i) {
        float dot[4][8];
#pragma unroll
        for (int r = 0; r < 4; ++r)
#pragma unroll
            for (int c = 0; c < 8; ++c) dot[r][c] = 0.f;
#pragma unroll
        for (int k = 0; k < KRANK; ++k) {
            f32x4 uv = *(const f32x4*)&us[i * 16 + k][to];
            f32x4 v0 = *(const f32x4*)&vts[i * 16 + k][tc];
            f32x4 v1 = *(const f32x4*)&vts[i * 16 + k][tc + 4];
#pragma unroll
            for (int r = 0; r < 4; ++r) {
#pragma unroll
                for (int c = 0; c < 4; ++c) {
                    dot[r][c]     += uv[r] * v0[c];
                    dot[r][c + 4] += uv[r] * v1[c];
                }
            }
        }
#pragma unroll
        for (int r = 0; r < 4; ++r) {
            unsigned byte = (unsigned)qw[i * QW_PLANE + (((o0 + to + r) * IN_F + c0 + tc) >> 3)];
#pragma unroll
            for (int c = 0; c < 8; ++c)
                wacc[r][c] += ((byte >> c) & 1u) ? dot[r][c] : -dot[r][c];
        }
    }
#pragma unroll
    for (int r = 0; r < 4; ++r) {
        short8 o8;
#pragma unroll
        for (int c = 0; c < 8; ++c) o8[c] = f2bf(wacc[r][c]);
        *(short8*)&wb[(size_t)(o0 + to + r) * IN_F + c0 + tc] = o8;
    }
}

// ---------------------------------------------------------------------------
// GEMM: R14 geometry + BALANCED per-phase LDS service (6 wave-reads/phase)
// via quadrant re-order Q00->Q01->Q11->Q10 (shortens a0/b0 live ranges so
// next-tile reads can spread into ph3/ph4). Gates: VMC(4)@ph2-end (proves
// A(T+1)), VMC(2)@ph3-end (proves B(T+1)), both VMC->BAR. MFMA kk-outer
// (same-acc writes 8 apart). All K-loop instructions volatile asm.
// ---------------------------------------------------------------------------
__global__ __launch_bounds__(512, 2) void gemm256_kernel(
    const short* __restrict__ A, const short* __restrict__ B, float* __restrict__ C) {
    extern __shared__ short lds[];

    const int t = threadIdx.x;
    const int lane = t & 63, wid = t >> 6;
    const int wr = wid >> 2, wc = wid & 3;       // 2 x 4 wave grid, wave 128x64
    const int fr = lane & 15, fq = lane >> 4;

    const int bid = blockIdx.x;
    const int cpx = gridDim.x >> 3;              // grid 1376 % 8 == 0
    const int swzb = (bid & 7) * cpx + (bid >> 3);
    const int bm = swzb / NBN, bn = swzb % NBN;
    const long row0 = (long)bm * 256, col0 = (long)bn * 256;

    // ---- fragment read bases: 8-granule perm, two kk base addresses
    const int f7 = fr & 7;
    const int g0 = fq ^ f7;
    const int g1 = (4 + fq) ^ f7;
    const int arow = (wr * 128 + fr) * 64;
    const int brow = (wc * 64 + fr) * 64;
    const unsigned av0 = (unsigned)(size_t)((__attribute__((address_space(3))) short*)lds + arow + g0 * 8);
    const unsigned av1 = (unsigned)(size_t)((__attribute__((address_space(3))) short*)lds + arow + g1 * 8);
    const unsigned bv0 = (unsigned)(size_t)((__attribute__((address_space(3))) short*)lds + 32768 + brow + g0 * 8);
    const unsigned bv1 = (unsigned)(size_t)((__attribute__((address_space(3))) short*)lds + 32768 + brow + g1 * 8);

    // ---- staging: linear LDS dest, inverse-swizzled global source
    const int sswz = (((t & 7) ^ ((t >> 3) & 7)) << 3);
    const short* pA = A + (row0 + (t >> 3)) * (size_t)K_DIM + sswz;
    const short* pB = B + (col0 + (t >> 3)) * (size_t)K_DIM + sswz;

    f32x4 acc[8][4];
#pragma unroll
    for (int m = 0; m < 8; ++m)
#pragma unroll
        for (int n = 0; n < 4; ++n) acc[m][n] = (f32x4)0.f;

    short8 a0[8], a1[8], b0[4], b1[4];   // a: [kk*4+m], b: [kk*2+n]

#define AOFF(P, MH, M) (((P) * 16384 + (MH) * 4096 + (M) * 1024) * 2)
#define BOFF(P, NH, N) (((P) * 16384 + (NH) * 2048 + (N) * 1024) * 2)

#define STGA(P, H, OFFB) do {                                               \
    async16(&lds[(P) * 16384 + (2 * (H)) * 4096 + t * 8],                   \
            (const char*)(pA + (size_t)(2 * (H)) * 64 * K_DIM) + (OFFB));   \
    async16(&lds[(P) * 16384 + (2 * (H) + 1) * 4096 + t * 8],               \
            (const char*)(pA + (size_t)(2 * (H) + 1) * 64 * K_DIM) + (OFFB)); \
} while (0)
#define STGB(P, H, OFFB) do {                                               \
    async16(&lds[32768 + (P) * 16384 + (2 * (H)) * 4096 + t * 8],           \
            (const char*)(pB + (size_t)(2 * (H)) * 64 * K_DIM) + (OFFB));   \
    async16(&lds[32768 + (P) * 16384 + (2 * (H) + 1) * 4096 + t * 8],       \
            (const char*)(pB + (size_t)(2 * (H) + 1) * 64 * K_DIM) + (OFFB)); \
} while (0)

// 4-MFMA group: rows MB,MB+1 x cols n0,n1 at kk-half KH (acc reuse 8 apart)
#define MFG(ASET, BSET, MH, NH, KH, MB) do {                                \
    MFA(acc[(MH) * 4 + (MB) + 0][(NH) * 2 + 0], ASET[(KH) * 4 + (MB) + 0], BSET[(KH) * 2 + 0]); \
    MFA(acc[(MH) * 4 + (MB) + 0][(NH) * 2 + 1], ASET[(KH) * 4 + (MB) + 0], BSET[(KH) * 2 + 1]); \
    MFA(acc[(MH) * 4 + (MB) + 1][(NH) * 2 + 0], ASET[(KH) * 4 + (MB) + 1], BSET[(KH) * 2 + 0]); \
    MFA(acc[(MH) * 4 + (MB) + 1][(NH) * 2 + 1], ASET[(KH) * 4 + (MB) + 1], BSET[(KH) * 2 + 1]); \
} while (0)

// one K-tile. Quadrant order Q00(a0,b0) Q01(a0,b1) Q11(a1,b1) Q10(a1,b0).
// Reads: ph1 {b1 x4, a1[0],[4]}, ph2 {a1 rest x6}, ph3 {a0' x6},
// ph4 {a0'[3],[7] early; b0' x4 after last b0 use}. 6/6/6/6.
#define TILE(P, Q, OFFB, OFFA, SB, SA, HG2, G2V, HG3, G3V, NEXT) do {       \
    /* ph1: Q00 */                                                          \
    LGKM0();                                                                \
    if (SB) STGB(Q, 0, OFFB);                                               \
    PRIO1();                                                                \
    MFG(a0, b0, 0, 0, 0, 0);                                                \
    DSR(b1[0], bv0, BOFF(P, 1, 0)); DSR(b1[1], bv0, BOFF(P, 1, 1));         \
    MFG(a0, b0, 0, 0, 0, 2);                                                \
    DSR(b1[2], bv1, BOFF(P, 1, 0)); DSR(b1[3], bv1, BOFF(P, 1, 1));         \
    MFG(a0, b0, 0, 0, 1, 0);                                                \
    DSR(a1[0], av0, AOFF(P, 1, 0)); DSR(a1[4], av1, AOFF(P, 1, 0));         \
    MFG(a0, b0, 0, 0, 1, 2);                                                \
    PRIO0(); BAR();                                                         \
    /* ph2: Q01 */                                                          \
    LGKM0();                                                                \
    if (SB) STGB(Q, 1, OFFB);                                               \
    PRIO1();                                                                \
    MFG(a0, b1, 0, 1, 0, 0);                                                \
    DSR(a1[1], av0, AOFF(P, 1, 1)); DSR(a1[5], av1, AOFF(P, 1, 1));         \
    MFG(a0, b1, 0, 1, 0, 2);                                                \
    DSR(a1[2], av0, AOFF(P, 1, 2)); DSR(a1[6], av1, AOFF(P, 1, 2));         \
    MFG(a0, b1, 0, 1, 1, 0);                                                \
    DSR(a1[3], av0, AOFF(P, 1, 3)); DSR(a1[7], av1, AOFF(P, 1, 3));         \
    MFG(a0, b1, 0, 1, 1, 2);                                                \
    PRIO0();                                                                \
    if (HG2) { VMC(G2V); }                                                  \
    BAR();                                                                  \
    /* ph3: Q11; a0 dead -> read next-tile a0' (A(T+1) proven by ph2 gate) */ \
    LGKM0();                                                                \
    if (SA) STGA(P, 0, OFFA);                                               \
    PRIO1();                                                                \
    MFG(a1, b1, 1, 1, 0, 0);                                                \
    if (NEXT) { DSR(a0[0], av0, AOFF(Q, 0, 0)); DSR(a0[4], av1, AOFF(Q, 0, 0)); } \
    MFG(a1, b1, 1, 1, 0, 2);                                                \
    if (NEXT) { DSR(a0[1], av0, AOFF(Q, 0, 1)); DSR(a0[5], av1, AOFF(Q, 0, 1)); } \
    MFG(a1, b1, 1, 1, 1, 0);                                                \
    if (NEXT) { DSR(a0[2], av0, AOFF(Q, 0, 2)); DSR(a0[6], av1, AOFF(Q, 0, 2)); } \
    MFG(a1, b1, 1, 1, 1, 2);                                                \
    PRIO0();                                                                \
    if (HG3) { VMC(G3V); }                                                  \
    BAR();                                                                  \
    /* ph4: Q10; b0' reads AFTER last b0-consuming MFMA */                  \
    if (SA) STGA(P, 1, OFFA);                                               \
    PRIO1();                                                                \
    MFG(a1, b0, 1, 0, 0, 0);                                                \
    if (NEXT) { DSR(a0[3], av0, AOFF(Q, 0, 3)); DSR(a0[7], av1, AOFF(Q, 0, 3)); } \
    MFG(a1, b0, 1, 0, 0, 2);                                                \
    MFG(a1, b0, 1, 0, 1, 0);                                                \
    MFG(a1, b0, 1, 0, 1, 2);                                                \
    if (NEXT) {                                                             \
        DSR(b0[0], bv0, BOFF(Q, 0, 0)); DSR(b0[1], bv0, BOFF(Q, 0, 1));     \
        DSR(b0[2], bv1, BOFF(Q, 0, 0)); DSR(b0[3], bv1, BOFF(Q, 0, 1));     \
    }                                                                       \
    PRIO0(); BAR();                                                         \
} while (0)

    // ---- prologue: A(0),B(0) -> buf0; A(1) -> buf1 (12 gll); gate; pre-read
    STGA(0, 0, 0); STGA(0, 1, 0);
    STGB(0, 0, 0); STGB(0, 1, 0);
    STGA(1, 0, 128); STGA(1, 1, 128);
    VMC(4);          // A(0)+B(0) landed; A(1) in flight
    BAR();
    DSR(a0[0], av0, AOFF(0, 0, 0)); DSR(a0[4], av1, AOFF(0, 0, 0));
    DSR(a0[1], av0, AOFF(0, 0, 1)); DSR(a0[5], av1, AOFF(0, 0, 1));
    DSR(a0[2], av0, AOFF(0, 0, 2)); DSR(a0[6], av1, AOFF(0, 0, 2));
    DSR(a0[3], av0, AOFF(0, 0, 3)); DSR(a0[7], av1, AOFF(0, 0, 3));
    DSR(b0[0], bv0, BOFF(0, 0, 0)); DSR(b0[1], bv0, BOFF(0, 0, 1));
    DSR(b0[2], bv1, BOFF(0, 0, 0)); DSR(b0[3], bv1, BOFF(0, 0, 1));

    // ---- main loop: 31 iters x 2 tiles (T0..T61)
    for (int it = 0; it < 31; ++it) {
        TILE(0, 1, 128, 256, 1, 1, 1, 4, 1, 2, 1);   // even tile
        TILE(1, 0, 256, 384, 1, 1, 1, 4, 1, 2, 1);   // odd tile
        pA += 128; pB += 128;   // +256 B = 2 K-tiles
    }

    // ---- tail T62 (P=0): stages only B(63); ph3-end gate drains all (VMC 0)
    TILE(0, 1, 128, 0, 1, 0, 1, 4, 1, 0, 1);
    // ---- tail T63 (P=1): no stages, no gates, no next-tile reads
    TILE(1, 0, 0, 0, 0, 0, 0, 0, 0, 0, 0);

    // ---- epilogue: C/D layout col = lane&15, row = (lane>>4)*4 + j
#pragma unroll
    for (int m = 0; m < 8; ++m) {
#pragma unroll
        for (int n = 0; n < 4; ++n) {
            f32x4 v = acc[m][n];
            long r0 = row0 + wr * 128 + m * 16 + fq * 4;
            long cc = col0 + wc * 64 + n * 16 + fr;
#pragma unroll
            for (int jj = 0; jj < 4; ++jj)
                C[(size_t)(r0 + jj) * N_DIM + cc] = v[jj];
        }
    }
#undef STGA
#undef STGB
#undef MFG
#undef TILE
#undef AOFF
#undef BOFF
}

// ---------------------------------------------------------------------------
extern "C" void kernel_launch(void* const* d_in, const int* in_sizes, int n_in,
                              void* d_out, int out_size, void* d_ws, size_t ws_size,
                              hipStream_t stream) {
    const float* x  = (const float*)d_in[0];
    const int*   qw = (const int*)d_in[1];
    const float* u  = (const float*)d_in[2];
    const float* vt = (const float*)d_in[3];
    float* out = (float*)d_out;

    const size_t wb_bytes = (size_t)OUT_F * IN_F * 2;
    short* wb = (short*)d_ws;
    short* xb = (short*)((char*)d_ws + wb_bytes);

    (void)hipFuncSetAttribute((const void*)gemm256_kernel,
                              hipFuncAttributeMaxDynamicSharedMemorySize, 131072);

    hipLaunchKernelGGL(prep_kernel, dim3(RW_BLOCKS + CV_BLOCKS), dim3(256), 0, stream,
                       x, qw, u, vt, xb, wb);
    hipLaunchKernelGGL(gemm256_kernel, dim3((M_DIM / 256) * (N_DIM / 256)), dim3(512), 131072,
                       stream, xb, wb, out);
}